// Round 6
// baseline (577.151 us; speedup 1.0000x reference)
//
#include <hip/hip_runtime.h>
#include <hip/hip_bf16.h>

#define NN 16384
#define NE 524288
#define FIN 512
#define HD 256
#define HD2 128

typedef __attribute__((ext_vector_type(8))) short bfrag;   // 8 bf16 = 4 VGPRs
typedef __attribute__((ext_vector_type(4))) float ffrag;   // 4 f32 acc

union U8 { ushort u[8]; uint4 v; };

static __device__ __forceinline__ ushort f2bf(float f) {
    uint u = __float_as_uint(f);
    return (ushort)((u + 0x7fff + ((u >> 16) & 1)) >> 16);  // RNE
}
static __device__ __forceinline__ float bf2f(ushort h) {
    return __uint_as_float(((uint)h) << 16);
}

// ---------------- CSR build ----------------
__global__ __launch_bounds__(256) void count_deg_kernel(const int* __restrict__ col,
                                                        int* __restrict__ cnt, int E) {
    int e = blockIdx.x * blockDim.x + threadIdx.x;
    if (e < E) atomicAdd(&cnt[col[e]], 1);
}

__global__ __launch_bounds__(256) void finish_dis_kernel(const int* __restrict__ cnt,
                                                         float* __restrict__ dis, int n) {
    int i = blockIdx.x * blockDim.x + threadIdx.x;
    if (i < n) dis[i] = rsqrtf((float)cnt[i] + 1.0f);
}

__global__ __launch_bounds__(256) void scan_kernel(const int* __restrict__ cnt,
                                                   int* __restrict__ off) {
    __shared__ int part[256];
    const int t = threadIdx.x;
    const int base = t * 64;
    int s = 0;
#pragma unroll 4
    for (int j = 0; j < 64; ++j) s += cnt[base + j];
    part[t] = s;
    __syncthreads();
    for (int d = 1; d < 256; d <<= 1) {
        int v = (t >= d) ? part[t - d] : 0;
        __syncthreads();
        part[t] += v;
        __syncthreads();
    }
    int run = (t == 0) ? 0 : part[t - 1];
    for (int j = 0; j < 64; ++j) {
        off[base + j] = run;
        run += cnt[base + j];
    }
    if (t == 255) off[NN] = run;
}

// pack (src, weight-bits) per edge
__global__ __launch_bounds__(256) void fill_kernel(const int* __restrict__ ei,
                                                   const int* __restrict__ off,
                                                   int* __restrict__ cur,
                                                   const float* __restrict__ dis,
                                                   int2* __restrict__ ew, int E) {
    int e = blockIdx.x * blockDim.x + threadIdx.x;
    if (e >= E) return;
    int r = ei[e], c = ei[E + e];
    int pos = off[c] + atomicAdd(&cur[c], 1);
    int2 p; p.x = r; p.y = __float_as_int(dis[r]);
    ew[pos] = p;
}

// ---------------- hi/lo bf16 conversions (segmented+swizzled layout) ----------------
__global__ __launch_bounds__(256) void conv_x_kernel(const float* __restrict__ x,
                                                     ushort* __restrict__ xhl) {
    const int t = blockIdx.x * 256 + threadIdx.x;   // NN*64
    const int r = t >> 6, ci = t & 63;
    const int seg = ci >> 3, c = ci & 7;
    const float* src = x + (size_t)r * FIN + ci * 8;
    U8 hi, lo;
#pragma unroll
    for (int u = 0; u < 8; ++u) {
        float v = src[u];
        ushort h = f2bf(v);
        hi.u[u] = h;
        lo.u[u] = f2bf(v - bf2f(h));
    }
    ushort* dst = xhl + (size_t)r * (FIN * 2) + seg * 128 + ((c ^ (r & 7)) * 8);
    *(uint4*)dst = hi.v;
    *(uint4*)(dst + 64) = lo.v;
}

__global__ __launch_bounds__(256) void conv_w_kernel(const float* __restrict__ Wa,
                                                     const float* __restrict__ Wb,
                                                     ushort* __restrict__ whl,
                                                     int Kfeat, int cshift) {
    const int t = blockIdx.x * 256 + threadIdx.x;   // 256 * Kfeat/8
    const int n = t >> cshift, ci = t & ((1 << cshift) - 1);
    const int seg = ci >> 3, c = ci & 7;
    U8 hi, lo;
#pragma unroll
    for (int u = 0; u < 8; ++u) {
        int k = ci * 8 + u;
        float v;
        if (Wb) v = (n < HD2) ? Wa[(size_t)k * HD2 + n] : Wb[(size_t)k * HD2 + (n - HD2)];
        else    v = Wa[(size_t)k * HD + n];
        ushort h = f2bf(v);
        hi.u[u] = h;
        lo.u[u] = f2bf(v - bf2f(h));
    }
    ushort* dst = whl + (size_t)n * (Kfeat * 2) + seg * 128 + ((c ^ (n & 7)) * 8);
    *(uint4*)dst = hi.v;
    *(uint4*)(dst + 64) = lo.v;
}

// ---------------- generic hi/lo GEMM (3-product): C[M][256] = Ahl . Bhl^T ----------------
__global__ __launch_bounds__(256, 2) void hl_gemm_kernel(const ushort* __restrict__ A,
                                                         const ushort* __restrict__ B,
                                                         float* __restrict__ C,
                                                         int nseg) {
    __shared__ ushort Ash[128 * 128];
    __shared__ ushort Bsh[128 * 128];
    const int tid = threadIdx.x;
    const int lane = tid & 63, wid = tid >> 6;
    const int rA0 = blockIdx.y * 128, cB0 = blockIdx.x * 128;
    const int rowush = nseg * 128;
    const int wm = (wid >> 1) * 64, wn = (wid & 1) * 64;
    const int fr = lane & 15, g = lane >> 4;

    ffrag acc[4][4];
#pragma unroll
    for (int i = 0; i < 4; ++i)
#pragma unroll
        for (int j = 0; j < 4; ++j) acc[i][j] = (ffrag){0.f, 0.f, 0.f, 0.f};

    for (int s = 0; s < nseg; ++s) {
        if (s) __syncthreads();
#pragma unroll
        for (int it = 0; it < 8; ++it) {
            int idx = it * 256 + tid;
            int row = idx >> 4, c16 = idx & 15;
            *(uint4*)&Ash[idx * 8] = *(const uint4*)&A[(size_t)(rA0 + row) * rowush + s * 128 + c16 * 8];
            *(uint4*)&Bsh[idx * 8] = *(const uint4*)&B[(size_t)(cB0 + row) * rowush + s * 128 + c16 * 8];
        }
        __syncthreads();
#pragma unroll
        for (int m = 0; m < 2; ++m) {
            bfrag ah[4], al[4], bh[4], bl[4];
            const int sw = ((m * 4 + g) ^ (fr & 7)) * 8;
#pragma unroll
            for (int mf = 0; mf < 4; ++mf) {
                const int base = (wm + mf * 16 + fr) * 128;
                ah[mf] = *(const bfrag*)&Ash[base + sw];
                al[mf] = *(const bfrag*)&Ash[base + 64 + sw];
            }
#pragma unroll
            for (int nf = 0; nf < 4; ++nf) {
                const int base = (wn + nf * 16 + fr) * 128;
                bh[nf] = *(const bfrag*)&Bsh[base + sw];
                bl[nf] = *(const bfrag*)&Bsh[base + 64 + sw];
            }
#pragma unroll
            for (int mf = 0; mf < 4; ++mf)
#pragma unroll
                for (int nf = 0; nf < 4; ++nf) {
                    acc[mf][nf] = __builtin_amdgcn_mfma_f32_16x16x32_bf16(ah[mf], bh[nf], acc[mf][nf], 0, 0, 0);
                    acc[mf][nf] = __builtin_amdgcn_mfma_f32_16x16x32_bf16(ah[mf], bl[nf], acc[mf][nf], 0, 0, 0);
                    acc[mf][nf] = __builtin_amdgcn_mfma_f32_16x16x32_bf16(al[mf], bh[nf], acc[mf][nf], 0, 0, 0);
                }
        }
    }
    const size_t row0 = (size_t)rA0 + wm;
    const int col0 = cB0 + wn;
#pragma unroll
    for (int mf = 0; mf < 4; ++mf)
#pragma unroll
        for (int reg = 0; reg < 4; ++reg) {
            float* outp = C + (row0 + mf * 16 + g * 4 + reg) * HD + col0 + fr;
#pragma unroll
            for (int nf = 0; nf < 4; ++nf) outp[nf * 16] = acc[mf][nf][reg];
        }
}

// ---------------- gather layer 1: relu(bias + norm-agg) -> h_hl ----------------
__global__ __launch_bounds__(256) void gather0_kernel(const int* __restrict__ off,
                                                      const int2* __restrict__ ew,
                                                      const float* __restrict__ dis,
                                                      const float* __restrict__ A,
                                                      const float* __restrict__ bias,
                                                      ushort* __restrict__ hhl) {
    const int wave = (blockIdx.x * blockDim.x + threadIdx.x) >> 6;
    const int lane = threadIdx.x & 63;
    if (wave >= NN) return;
    const int i = wave;
    const float di = dis[i];
    const int j = lane * 4;
    float4 a0 = *(const float4*)&A[(size_t)i * HD + j];
    a0.x *= di; a0.y *= di; a0.z *= di; a0.w *= di;
    float4 a1 = make_float4(0.f, 0.f, 0.f, 0.f);
    const int k1 = off[i + 1];
    int k = off[i];
    for (; k + 2 <= k1; k += 2) {
        const int2 e0 = ew[k], e1 = ew[k + 1];
        const float w0 = __int_as_float(e0.y), w1 = __int_as_float(e1.y);
        const float4 v0 = *(const float4*)&A[(size_t)e0.x * HD + j];
        const float4 v1 = *(const float4*)&A[(size_t)e1.x * HD + j];
        a0.x += w0 * v0.x; a0.y += w0 * v0.y; a0.z += w0 * v0.z; a0.w += w0 * v0.w;
        a1.x += w1 * v1.x; a1.y += w1 * v1.y; a1.z += w1 * v1.z; a1.w += w1 * v1.w;
    }
    if (k < k1) {
        const int2 e0 = ew[k];
        const float w0 = __int_as_float(e0.y);
        const float4 v0 = *(const float4*)&A[(size_t)e0.x * HD + j];
        a0.x += w0 * v0.x; a0.y += w0 * v0.y; a0.z += w0 * v0.z; a0.w += w0 * v0.w;
    }
    a0.x += a1.x; a0.y += a1.y; a0.z += a1.z; a0.w += a1.w;
    const float4 bb = *(const float4*)&bias[j];
    a0.x = fmaxf(a0.x * di + bb.x, 0.f);
    a0.y = fmaxf(a0.y * di + bb.y, 0.f);
    a0.z = fmaxf(a0.z * di + bb.z, 0.f);
    a0.w = fmaxf(a0.w * di + bb.w, 0.f);
    ushort4 hv, lv;
    hv.x = f2bf(a0.x); lv.x = f2bf(a0.x - bf2f(hv.x));
    hv.y = f2bf(a0.y); lv.y = f2bf(a0.y - bf2f(hv.y));
    hv.z = f2bf(a0.z); lv.z = f2bf(a0.z - bf2f(hv.z));
    hv.w = f2bf(a0.w); lv.w = f2bf(a0.w - bf2f(hv.w));
    const int seg = lane >> 4, c = (lane >> 1) & 7, half = (lane & 1) * 4;
    ushort* dst = hhl + (size_t)i * (HD * 2) + seg * 128 + ((c ^ (i & 7)) * 8) + half;
    *(ushort4*)dst = hv;
    *(ushort4*)(dst + 64) = lv;
}

// ---------------- gather layer 2: mu/logvar f32 out + z_hl ----------------
__global__ __launch_bounds__(256) void gather1_kernel(const int* __restrict__ off,
                                                      const int2* __restrict__ ew,
                                                      const float* __restrict__ dis,
                                                      const float* __restrict__ A,
                                                      const float* __restrict__ b1,
                                                      const float* __restrict__ b2,
                                                      float* __restrict__ out_mu,
                                                      float* __restrict__ out_lv,
                                                      ushort* __restrict__ zhl) {
    const int wave = (blockIdx.x * blockDim.x + threadIdx.x) >> 6;
    const int lane = threadIdx.x & 63;
    if (wave >= NN) return;
    const int i = wave;
    const float di = dis[i];
    const int j = lane * 4;
    float4 a0 = *(const float4*)&A[(size_t)i * HD + j];
    a0.x *= di; a0.y *= di; a0.z *= di; a0.w *= di;
    float4 a1 = make_float4(0.f, 0.f, 0.f, 0.f);
    const int k1 = off[i + 1];
    int k = off[i];
    for (; k + 2 <= k1; k += 2) {
        const int2 e0 = ew[k], e1 = ew[k + 1];
        const float w0 = __int_as_float(e0.y), w1 = __int_as_float(e1.y);
        const float4 v0 = *(const float4*)&A[(size_t)e0.x * HD + j];
        const float4 v1 = *(const float4*)&A[(size_t)e1.x * HD + j];
        a0.x += w0 * v0.x; a0.y += w0 * v0.y; a0.z += w0 * v0.z; a0.w += w0 * v0.w;
        a1.x += w1 * v1.x; a1.y += w1 * v1.y; a1.z += w1 * v1.z; a1.w += w1 * v1.w;
    }
    if (k < k1) {
        const int2 e0 = ew[k];
        const float w0 = __int_as_float(e0.y);
        const float4 v0 = *(const float4*)&A[(size_t)e0.x * HD + j];
        a0.x += w0 * v0.x; a0.y += w0 * v0.y; a0.z += w0 * v0.z; a0.w += w0 * v0.w;
    }
    ffrag r;
    r[0] = (a0.x + a1.x) * di;
    r[1] = (a0.y + a1.y) * di;
    r[2] = (a0.z + a1.z) * di;
    r[3] = (a0.w + a1.w) * di;
    if (lane < 32) {
        const float4 bb = *(const float4*)&b1[j];
        r[0] += bb.x; r[1] += bb.y; r[2] += bb.z; r[3] += bb.w;
        __builtin_nontemporal_store(r, (ffrag*)&out_mu[(size_t)i * HD2 + j]);
        ushort4 hv, lv;
        hv.x = f2bf(r[0]); lv.x = f2bf(r[0] - bf2f(hv.x));
        hv.y = f2bf(r[1]); lv.y = f2bf(r[1] - bf2f(hv.y));
        hv.z = f2bf(r[2]); lv.z = f2bf(r[2] - bf2f(hv.z));
        hv.w = f2bf(r[3]); lv.w = f2bf(r[3] - bf2f(hv.w));
        const int seg = lane >> 4, c = (lane >> 1) & 7, half = (lane & 1) * 4;
        ushort* dst = zhl + (size_t)i * (HD2 * 2) + seg * 128 + ((c ^ (i & 7)) * 8) + half;
        *(ushort4*)dst = hv;
        *(ushort4*)(dst + 64) = lv;
    } else {
        const int jj = j - HD2;
        const float4 bb = *(const float4*)&b2[jj];
        r[0] += bb.x; r[1] += bb.y; r[2] += bb.z; r[3] += bb.w;
        __builtin_nontemporal_store(r, (ffrag*)&out_lv[(size_t)i * HD2 + jj]);
    }
}

// ---------------- Adj = z z^T, triangular + mirror, 3-product, NT stores ----------------
__global__ __launch_bounds__(256, 2) void zz_tri_kernel(const ushort* __restrict__ Z,
                                                        float* __restrict__ adj) {
    const int bm = blockIdx.y, bn = blockIdx.x;
    if (bn < bm) return;  // upper triangle only
    __shared__ ushort Ash[128 * 128];
    __shared__ ushort Bsh[128 * 128];
    const int tid = threadIdx.x;
    const int lane = tid & 63, wid = tid >> 6;
    const int wm = (wid >> 1) * 64, wn = (wid & 1) * 64;
    const int fr = lane & 15, g = lane >> 4;

    ffrag acc[4][4];
#pragma unroll
    for (int i = 0; i < 4; ++i)
#pragma unroll
        for (int j = 0; j < 4; ++j) acc[i][j] = (ffrag){0.f, 0.f, 0.f, 0.f};

#pragma unroll
    for (int s = 0; s < 2; ++s) {
        if (s) __syncthreads();
#pragma unroll
        for (int it = 0; it < 8; ++it) {
            int idx = it * 256 + tid;
            int row = idx >> 4, c16 = idx & 15;
            *(uint4*)&Ash[idx * 8] = *(const uint4*)&Z[(size_t)(bm * 128 + row) * 256 + s * 128 + c16 * 8];
            *(uint4*)&Bsh[idx * 8] = *(const uint4*)&Z[(size_t)(bn * 128 + row) * 256 + s * 128 + c16 * 8];
        }
        __syncthreads();
#pragma unroll
        for (int m = 0; m < 2; ++m) {
            bfrag ah[4], al[4], bh[4], bl[4];
            const int sw = ((m * 4 + g) ^ (fr & 7)) * 8;
#pragma unroll
            for (int mf = 0; mf < 4; ++mf) {
                const int base = (wm + mf * 16 + fr) * 128;
                ah[mf] = *(const bfrag*)&Ash[base + sw];
                al[mf] = *(const bfrag*)&Ash[base + 64 + sw];
            }
#pragma unroll
            for (int nf = 0; nf < 4; ++nf) {
                const int base = (wn + nf * 16 + fr) * 128;
                bh[nf] = *(const bfrag*)&Bsh[base + sw];
                bl[nf] = *(const bfrag*)&Bsh[base + 64 + sw];
            }
#pragma unroll
            for (int mf = 0; mf < 4; ++mf)
#pragma unroll
                for (int nf = 0; nf < 4; ++nf) {
                    acc[mf][nf] = __builtin_amdgcn_mfma_f32_16x16x32_bf16(ah[mf], bh[nf], acc[mf][nf], 0, 0, 0);
                    acc[mf][nf] = __builtin_amdgcn_mfma_f32_16x16x32_bf16(ah[mf], bl[nf], acc[mf][nf], 0, 0, 0);
                    acc[mf][nf] = __builtin_amdgcn_mfma_f32_16x16x32_bf16(al[mf], bh[nf], acc[mf][nf], 0, 0, 0);
                }
        }
    }

    // normal store (upper tile), nontemporal
    const size_t row0 = (size_t)bm * 128 + wm;
    const int col0 = bn * 128 + wn;
#pragma unroll
    for (int mf = 0; mf < 4; ++mf)
#pragma unroll
        for (int reg = 0; reg < 4; ++reg) {
            float* outp = adj + (row0 + mf * 16 + g * 4 + reg) * NN + col0 + fr;
#pragma unroll
            for (int nf = 0; nf < 4; ++nf)
                __builtin_nontemporal_store(acc[mf][nf][reg], outp + nf * 16);
        }
    // mirror store (lower tile): the 4 regs are 4 consecutive cols -> vector NT store
    if (bm != bn) {
#pragma unroll
        for (int nf = 0; nf < 4; ++nf)
#pragma unroll
            for (int mf = 0; mf < 4; ++mf) {
                const size_t addr = ((size_t)bn * 128 + wn + nf * 16 + fr) * NN
                                  + (size_t)bm * 128 + wm + mf * 16 + g * 4;
                __builtin_nontemporal_store(acc[mf][nf], (ffrag*)&adj[addr]);
            }
    }
}

extern "C" void kernel_launch(void* const* d_in, const int* in_sizes, int n_in,
                              void* d_out, int out_size, void* d_ws, size_t ws_size,
                              hipStream_t stream) {
    const float* x     = (const float*)d_in[0];
    const int*   ei    = (const int*)d_in[1];
    const float* W_enc = (const float*)d_in[2];
    const float* b_enc = (const float*)d_in[3];
    const float* W1    = (const float*)d_in[4];
    const float* b1    = (const float*)d_in[5];
    const float* W2    = (const float*)d_in[6];
    const float* b2    = (const float*)d_in[7];

    float* out    = (float*)d_out;
    float* adj    = out;
    float* out_mu = out + (size_t)NN * NN;
    float* out_lv = out_mu + (size_t)NN * HD2;

    float*  ws    = (float*)d_ws;
    float*  dis   = ws;                                  // NN f32
    float*  bufA  = ws + NN;                             // NN*HD f32
    ushort* xhl   = (ushort*)(bufA + (size_t)NN * HD);   // NN*1024 ush
    ushort* hhl   = xhl;                                 // reuse after gemm1 (NN*512 ush)
    ushort* zhl   = xhl + (size_t)NN * 512;              // reuse tail (NN*256 ush)
    ushort* wencT = xhl + (size_t)NN * 1024;             // 256*1024 ush
    ushort* wcatT = wencT + 256 * 1024;                  // 256*512 ush
    int2*   ew    = (int2*)(wcatT + 256 * 512);          // NE int2
    int*    icnt  = (int*)(ew + NE);                     // NN
    int*    off   = icnt + NN;                           // NN+1
    int*    cur   = off + NN + 1;                        // NN

    // CSR build
    hipMemsetAsync(icnt, 0, NN * sizeof(int), stream);
    hipMemsetAsync(cur, 0, NN * sizeof(int), stream);
    count_deg_kernel<<<NE / 256, 256, 0, stream>>>(ei + NE, icnt, NE);
    finish_dis_kernel<<<NN / 256, 256, 0, stream>>>(icnt, dis, NN);
    scan_kernel<<<1, 256, 0, stream>>>(icnt, off);
    fill_kernel<<<NE / 256, 256, 0, stream>>>(ei, off, cur, dis, ew, NE);

    // hi/lo conversions
    conv_x_kernel<<<NN * 64 / 256, 256, 0, stream>>>(x, xhl);
    conv_w_kernel<<<64, 256, 0, stream>>>(W_enc, nullptr, wencT, FIN, 6);
    conv_w_kernel<<<32, 256, 0, stream>>>(W1, W2, wcatT, HD, 5);

    // layer 1: XW (MFMA) -> gather+relu -> h_hl
    hl_gemm_kernel<<<dim3(2, NN / 128), 256, 0, stream>>>(xhl, wencT, bufA, FIN / 64);
    gather0_kernel<<<NN * 64 / 256, 256, 0, stream>>>(off, ew, dis, bufA, b_enc, hhl);

    // layer 2: HW (MFMA) -> gather -> mu/logvar + z_hl
    hl_gemm_kernel<<<dim3(2, NN / 128), 256, 0, stream>>>(hhl, wcatT, bufA, HD / 64);
    gather1_kernel<<<NN * 64 / 256, 256, 0, stream>>>(off, ew, dis, bufA, b1, b2,
                                                      out_mu, out_lv, zhl);

    // Adj = z z^T (triangular + mirror)
    zz_tri_kernel<<<dim3(NN / 128, NN / 128), 256, 0, stream>>>(zhl, adj);
}

// Round 7
// 498.130 us; speedup vs baseline: 1.1586x; 1.1586x over previous
//
#include <hip/hip_runtime.h>
#include <hip/hip_bf16.h>

#define NN 16384
#define NE 524288
#define FIN 512
#define HD 256
#define HD2 128
#define NB 128  // NN/128 tile blocks per dim

typedef __attribute__((ext_vector_type(8))) short bfrag;   // 8 bf16 = 4 VGPRs
typedef __attribute__((ext_vector_type(4))) float ffrag;   // 4 f32 acc

union U8 { ushort u[8]; uint4 v; };

static __device__ __forceinline__ ushort f2bf(float f) {
    uint u = __float_as_uint(f);
    return (ushort)((u + 0x7fff + ((u >> 16) & 1)) >> 16);  // RNE
}
static __device__ __forceinline__ float bf2f(ushort h) {
    return __uint_as_float(((uint)h) << 16);
}

// ---------------- CSR build ----------------
__global__ __launch_bounds__(256) void count_deg_kernel(const int* __restrict__ col,
                                                        int* __restrict__ cnt, int E) {
    int e = blockIdx.x * blockDim.x + threadIdx.x;
    if (e < E) atomicAdd(&cnt[col[e]], 1);
}

__global__ __launch_bounds__(256) void finish_dis_kernel(const int* __restrict__ cnt,
                                                         float* __restrict__ dis, int n) {
    int i = blockIdx.x * blockDim.x + threadIdx.x;
    if (i < n) dis[i] = rsqrtf((float)cnt[i] + 1.0f);
}

__global__ __launch_bounds__(256) void scan_kernel(const int* __restrict__ cnt,
                                                   int* __restrict__ off) {
    __shared__ int part[256];
    const int t = threadIdx.x;
    const int base = t * 64;
    int s = 0;
#pragma unroll 4
    for (int j = 0; j < 64; ++j) s += cnt[base + j];
    part[t] = s;
    __syncthreads();
    for (int d = 1; d < 256; d <<= 1) {
        int v = (t >= d) ? part[t - d] : 0;
        __syncthreads();
        part[t] += v;
        __syncthreads();
    }
    int run = (t == 0) ? 0 : part[t - 1];
    for (int j = 0; j < 64; ++j) {
        off[base + j] = run;
        run += cnt[base + j];
    }
    if (t == 255) off[NN] = run;
}

// pack (src, weight-bits) per edge
__global__ __launch_bounds__(256) void fill_kernel(const int* __restrict__ ei,
                                                   const int* __restrict__ off,
                                                   int* __restrict__ cur,
                                                   const float* __restrict__ dis,
                                                   int2* __restrict__ ew, int E) {
    int e = blockIdx.x * blockDim.x + threadIdx.x;
    if (e >= E) return;
    int r = ei[e], c = ei[E + e];
    int pos = off[c] + atomicAdd(&cur[c], 1);
    int2 p; p.x = r; p.y = __float_as_int(dis[r]);
    ew[pos] = p;
}

// ---------------- hi/lo bf16 conversions (segmented+swizzled layout) ----------------
__global__ __launch_bounds__(256) void conv_x_kernel(const float* __restrict__ x,
                                                     ushort* __restrict__ xhl) {
    const int t = blockIdx.x * 256 + threadIdx.x;   // NN*64
    const int r = t >> 6, ci = t & 63;
    const int seg = ci >> 3, c = ci & 7;
    const float* src = x + (size_t)r * FIN + ci * 8;
    U8 hi, lo;
#pragma unroll
    for (int u = 0; u < 8; ++u) {
        float v = src[u];
        ushort h = f2bf(v);
        hi.u[u] = h;
        lo.u[u] = f2bf(v - bf2f(h));
    }
    ushort* dst = xhl + (size_t)r * (FIN * 2) + seg * 128 + ((c ^ (r & 7)) * 8);
    *(uint4*)dst = hi.v;
    *(uint4*)(dst + 64) = lo.v;
}

__global__ __launch_bounds__(256) void conv_w_kernel(const float* __restrict__ Wa,
                                                     const float* __restrict__ Wb,
                                                     ushort* __restrict__ whl,
                                                     int Kfeat, int cshift) {
    const int t = blockIdx.x * 256 + threadIdx.x;   // 256 * Kfeat/8
    const int n = t >> cshift, ci = t & ((1 << cshift) - 1);
    const int seg = ci >> 3, c = ci & 7;
    U8 hi, lo;
#pragma unroll
    for (int u = 0; u < 8; ++u) {
        int k = ci * 8 + u;
        float v;
        if (Wb) v = (n < HD2) ? Wa[(size_t)k * HD2 + n] : Wb[(size_t)k * HD2 + (n - HD2)];
        else    v = Wa[(size_t)k * HD + n];
        ushort h = f2bf(v);
        hi.u[u] = h;
        lo.u[u] = f2bf(v - bf2f(h));
    }
    ushort* dst = whl + (size_t)n * (Kfeat * 2) + seg * 128 + ((c ^ (n & 7)) * 8);
    *(uint4*)dst = hi.v;
    *(uint4*)(dst + 64) = lo.v;
}

// ---------------- generic hi/lo GEMM (3-product): C[M][256] = Ahl . Bhl^T ----------------
__global__ __launch_bounds__(256, 2) void hl_gemm_kernel(const ushort* __restrict__ A,
                                                         const ushort* __restrict__ B,
                                                         float* __restrict__ C,
                                                         int nseg) {
    __shared__ ushort Ash[128 * 128];
    __shared__ ushort Bsh[128 * 128];
    const int tid = threadIdx.x;
    const int lane = tid & 63, wid = tid >> 6;
    const int rA0 = blockIdx.y * 128, cB0 = blockIdx.x * 128;
    const int rowush = nseg * 128;
    const int wm = (wid >> 1) * 64, wn = (wid & 1) * 64;
    const int fr = lane & 15, g = lane >> 4;

    ffrag acc[4][4];
#pragma unroll
    for (int i = 0; i < 4; ++i)
#pragma unroll
        for (int j = 0; j < 4; ++j) acc[i][j] = (ffrag){0.f, 0.f, 0.f, 0.f};

    for (int s = 0; s < nseg; ++s) {
        if (s) __syncthreads();
#pragma unroll
        for (int it = 0; it < 8; ++it) {
            int idx = it * 256 + tid;
            int row = idx >> 4, c16 = idx & 15;
            *(uint4*)&Ash[idx * 8] = *(const uint4*)&A[(size_t)(rA0 + row) * rowush + s * 128 + c16 * 8];
            *(uint4*)&Bsh[idx * 8] = *(const uint4*)&B[(size_t)(cB0 + row) * rowush + s * 128 + c16 * 8];
        }
        __syncthreads();
#pragma unroll
        for (int m = 0; m < 2; ++m) {
            bfrag ah[4], al[4], bh[4], bl[4];
            const int sw = ((m * 4 + g) ^ (fr & 7)) * 8;
#pragma unroll
            for (int mf = 0; mf < 4; ++mf) {
                const int base = (wm + mf * 16 + fr) * 128;
                ah[mf] = *(const bfrag*)&Ash[base + sw];
                al[mf] = *(const bfrag*)&Ash[base + 64 + sw];
            }
#pragma unroll
            for (int nf = 0; nf < 4; ++nf) {
                const int base = (wn + nf * 16 + fr) * 128;
                bh[nf] = *(const bfrag*)&Bsh[base + sw];
                bl[nf] = *(const bfrag*)&Bsh[base + 64 + sw];
            }
#pragma unroll
            for (int mf = 0; mf < 4; ++mf)
#pragma unroll
                for (int nf = 0; nf < 4; ++nf) {
                    acc[mf][nf] = __builtin_amdgcn_mfma_f32_16x16x32_bf16(ah[mf], bh[nf], acc[mf][nf], 0, 0, 0);
                    acc[mf][nf] = __builtin_amdgcn_mfma_f32_16x16x32_bf16(ah[mf], bl[nf], acc[mf][nf], 0, 0, 0);
                    acc[mf][nf] = __builtin_amdgcn_mfma_f32_16x16x32_bf16(al[mf], bh[nf], acc[mf][nf], 0, 0, 0);
                }
        }
    }
    const size_t row0 = (size_t)rA0 + wm;
    const int col0 = cB0 + wn;
#pragma unroll
    for (int mf = 0; mf < 4; ++mf)
#pragma unroll
        for (int reg = 0; reg < 4; ++reg) {
            float* outp = C + (row0 + mf * 16 + g * 4 + reg) * HD + col0 + fr;
#pragma unroll
            for (int nf = 0; nf < 4; ++nf) outp[nf * 16] = acc[mf][nf][reg];
        }
}

// ---------------- gather layer 1: relu(bias + norm-agg) -> h_hl ----------------
__global__ __launch_bounds__(256) void gather0_kernel(const int* __restrict__ off,
                                                      const int2* __restrict__ ew,
                                                      const float* __restrict__ dis,
                                                      const float* __restrict__ A,
                                                      const float* __restrict__ bias,
                                                      ushort* __restrict__ hhl) {
    const int wave = (blockIdx.x * blockDim.x + threadIdx.x) >> 6;
    const int lane = threadIdx.x & 63;
    if (wave >= NN) return;
    const int i = wave;
    const float di = dis[i];
    const int j = lane * 4;
    float4 a0 = *(const float4*)&A[(size_t)i * HD + j];
    a0.x *= di; a0.y *= di; a0.z *= di; a0.w *= di;
    float4 a1 = make_float4(0.f, 0.f, 0.f, 0.f);
    const int k1 = off[i + 1];
    int k = off[i];
    for (; k + 2 <= k1; k += 2) {
        const int2 e0 = ew[k], e1 = ew[k + 1];
        const float w0 = __int_as_float(e0.y), w1 = __int_as_float(e1.y);
        const float4 v0 = *(const float4*)&A[(size_t)e0.x * HD + j];
        const float4 v1 = *(const float4*)&A[(size_t)e1.x * HD + j];
        a0.x += w0 * v0.x; a0.y += w0 * v0.y; a0.z += w0 * v0.z; a0.w += w0 * v0.w;
        a1.x += w1 * v1.x; a1.y += w1 * v1.y; a1.z += w1 * v1.z; a1.w += w1 * v1.w;
    }
    if (k < k1) {
        const int2 e0 = ew[k];
        const float w0 = __int_as_float(e0.y);
        const float4 v0 = *(const float4*)&A[(size_t)e0.x * HD + j];
        a0.x += w0 * v0.x; a0.y += w0 * v0.y; a0.z += w0 * v0.z; a0.w += w0 * v0.w;
    }
    a0.x += a1.x; a0.y += a1.y; a0.z += a1.z; a0.w += a1.w;
    const float4 bb = *(const float4*)&bias[j];
    a0.x = fmaxf(a0.x * di + bb.x, 0.f);
    a0.y = fmaxf(a0.y * di + bb.y, 0.f);
    a0.z = fmaxf(a0.z * di + bb.z, 0.f);
    a0.w = fmaxf(a0.w * di + bb.w, 0.f);
    ushort4 hv, lv;
    hv.x = f2bf(a0.x); lv.x = f2bf(a0.x - bf2f(hv.x));
    hv.y = f2bf(a0.y); lv.y = f2bf(a0.y - bf2f(hv.y));
    hv.z = f2bf(a0.z); lv.z = f2bf(a0.z - bf2f(hv.z));
    hv.w = f2bf(a0.w); lv.w = f2bf(a0.w - bf2f(hv.w));
    const int seg = lane >> 4, c = (lane >> 1) & 7, half = (lane & 1) * 4;
    ushort* dst = hhl + (size_t)i * (HD * 2) + seg * 128 + ((c ^ (i & 7)) * 8) + half;
    *(ushort4*)dst = hv;
    *(ushort4*)(dst + 64) = lv;
}

// ---------------- gather layer 2: mu/logvar f32 out + z_hl ----------------
__global__ __launch_bounds__(256) void gather1_kernel(const int* __restrict__ off,
                                                      const int2* __restrict__ ew,
                                                      const float* __restrict__ dis,
                                                      const float* __restrict__ A,
                                                      const float* __restrict__ b1,
                                                      const float* __restrict__ b2,
                                                      float* __restrict__ out_mu,
                                                      float* __restrict__ out_lv,
                                                      ushort* __restrict__ zhl) {
    const int wave = (blockIdx.x * blockDim.x + threadIdx.x) >> 6;
    const int lane = threadIdx.x & 63;
    if (wave >= NN) return;
    const int i = wave;
    const float di = dis[i];
    const int j = lane * 4;
    float4 a0 = *(const float4*)&A[(size_t)i * HD + j];
    a0.x *= di; a0.y *= di; a0.z *= di; a0.w *= di;
    float4 a1 = make_float4(0.f, 0.f, 0.f, 0.f);
    const int k1 = off[i + 1];
    int k = off[i];
    for (; k + 2 <= k1; k += 2) {
        const int2 e0 = ew[k], e1 = ew[k + 1];
        const float w0 = __int_as_float(e0.y), w1 = __int_as_float(e1.y);
        const float4 v0 = *(const float4*)&A[(size_t)e0.x * HD + j];
        const float4 v1 = *(const float4*)&A[(size_t)e1.x * HD + j];
        a0.x += w0 * v0.x; a0.y += w0 * v0.y; a0.z += w0 * v0.z; a0.w += w0 * v0.w;
        a1.x += w1 * v1.x; a1.y += w1 * v1.y; a1.z += w1 * v1.z; a1.w += w1 * v1.w;
    }
    if (k < k1) {
        const int2 e0 = ew[k];
        const float w0 = __int_as_float(e0.y);
        const float4 v0 = *(const float4*)&A[(size_t)e0.x * HD + j];
        a0.x += w0 * v0.x; a0.y += w0 * v0.y; a0.z += w0 * v0.z; a0.w += w0 * v0.w;
    }
    float4 r;
    r.x = (a0.x + a1.x) * di;
    r.y = (a0.y + a1.y) * di;
    r.z = (a0.z + a1.z) * di;
    r.w = (a0.w + a1.w) * di;
    if (lane < 32) {
        const float4 bb = *(const float4*)&b1[j];
        r.x += bb.x; r.y += bb.y; r.z += bb.z; r.w += bb.w;
        *(float4*)&out_mu[(size_t)i * HD2 + j] = r;
        ushort4 hv, lv;
        hv.x = f2bf(r.x); lv.x = f2bf(r.x - bf2f(hv.x));
        hv.y = f2bf(r.y); lv.y = f2bf(r.y - bf2f(hv.y));
        hv.z = f2bf(r.z); lv.z = f2bf(r.z - bf2f(hv.z));
        hv.w = f2bf(r.w); lv.w = f2bf(r.w - bf2f(hv.w));
        const int seg = lane >> 4, c = (lane >> 1) & 7, half = (lane & 1) * 4;
        ushort* dst = zhl + (size_t)i * (HD2 * 2) + seg * 128 + ((c ^ (i & 7)) * 8) + half;
        *(ushort4*)dst = hv;
        *(ushort4*)(dst + 64) = lv;
    } else {
        const int jj = j - HD2;
        const float4 bb = *(const float4*)&b2[jj];
        r.x += bb.x; r.y += bb.y; r.z += bb.z; r.w += bb.w;
        *(float4*)&out_lv[(size_t)i * HD2 + jj] = r;
    }
}

// ---------------- Adj = z z^T, 1D triangular grid + mirror, 3-product ----------------
__global__ __launch_bounds__(256, 2) void zz_tri_kernel(const ushort* __restrict__ Z,
                                                        float* __restrict__ adj) {
    // decode linear block id -> (bm, bn), bm <= bn
    const int t = blockIdx.x;
    int bm = (int)((257.0f - sqrtf(66049.0f - 8.0f * (float)t)) * 0.5f);
    while (bm * NB - bm * (bm - 1) / 2 > t) --bm;
    while ((bm + 1) * NB - (bm + 1) * bm / 2 <= t) ++bm;
    const int bn = bm + (t - (bm * NB - bm * (bm - 1) / 2));

    __shared__ ushort Ash[128 * 128];
    __shared__ ushort Bsh[128 * 128];
    const int tid = threadIdx.x;
    const int lane = tid & 63, wid = tid >> 6;
    const int wm = (wid >> 1) * 64, wn = (wid & 1) * 64;
    const int fr = lane & 15, g = lane >> 4;

    ffrag acc[4][4];
#pragma unroll
    for (int i = 0; i < 4; ++i)
#pragma unroll
        for (int j = 0; j < 4; ++j) acc[i][j] = (ffrag){0.f, 0.f, 0.f, 0.f};

#pragma unroll
    for (int s = 0; s < 2; ++s) {
        if (s) __syncthreads();
#pragma unroll
        for (int it = 0; it < 8; ++it) {
            int idx = it * 256 + tid;
            int row = idx >> 4, c16 = idx & 15;
            *(uint4*)&Ash[idx * 8] = *(const uint4*)&Z[(size_t)(bm * 128 + row) * 256 + s * 128 + c16 * 8];
            *(uint4*)&Bsh[idx * 8] = *(const uint4*)&Z[(size_t)(bn * 128 + row) * 256 + s * 128 + c16 * 8];
        }
        __syncthreads();
#pragma unroll
        for (int m = 0; m < 2; ++m) {
            bfrag ah[4], al[4], bh[4], bl[4];
            const int sw = ((m * 4 + g) ^ (fr & 7)) * 8;
#pragma unroll
            for (int mf = 0; mf < 4; ++mf) {
                const int base = (wm + mf * 16 + fr) * 128;
                ah[mf] = *(const bfrag*)&Ash[base + sw];
                al[mf] = *(const bfrag*)&Ash[base + 64 + sw];
            }
#pragma unroll
            for (int nf = 0; nf < 4; ++nf) {
                const int base = (wn + nf * 16 + fr) * 128;
                bh[nf] = *(const bfrag*)&Bsh[base + sw];
                bl[nf] = *(const bfrag*)&Bsh[base + 64 + sw];
            }
#pragma unroll
            for (int mf = 0; mf < 4; ++mf)
#pragma unroll
                for (int nf = 0; nf < 4; ++nf) {
                    acc[mf][nf] = __builtin_amdgcn_mfma_f32_16x16x32_bf16(ah[mf], bh[nf], acc[mf][nf], 0, 0, 0);
                    acc[mf][nf] = __builtin_amdgcn_mfma_f32_16x16x32_bf16(ah[mf], bl[nf], acc[mf][nf], 0, 0, 0);
                    acc[mf][nf] = __builtin_amdgcn_mfma_f32_16x16x32_bf16(al[mf], bh[nf], acc[mf][nf], 0, 0, 0);
                }
        }
    }

    // normal store (upper tile), cached
    const size_t row0 = (size_t)bm * 128 + wm;
    const int col0 = bn * 128 + wn;
#pragma unroll
    for (int mf = 0; mf < 4; ++mf)
#pragma unroll
        for (int reg = 0; reg < 4; ++reg) {
            float* outp = adj + (row0 + mf * 16 + g * 4 + reg) * NN + col0 + fr;
#pragma unroll
            for (int nf = 0; nf < 4; ++nf) outp[nf * 16] = acc[mf][nf][reg];
        }
    // mirror store (lower tile): the 4 regs are 4 consecutive cols -> float4 store
    if (bm != bn) {
#pragma unroll
        for (int nf = 0; nf < 4; ++nf)
#pragma unroll
            for (int mf = 0; mf < 4; ++mf) {
                const size_t addr = ((size_t)bn * 128 + wn + nf * 16 + fr) * NN
                                  + (size_t)bm * 128 + wm + mf * 16 + g * 4;
                *(float4*)&adj[addr] = *(float4*)&acc[mf][nf];
            }
    }
}

extern "C" void kernel_launch(void* const* d_in, const int* in_sizes, int n_in,
                              void* d_out, int out_size, void* d_ws, size_t ws_size,
                              hipStream_t stream) {
    const float* x     = (const float*)d_in[0];
    const int*   ei    = (const int*)d_in[1];
    const float* W_enc = (const float*)d_in[2];
    const float* b_enc = (const float*)d_in[3];
    const float* W1    = (const float*)d_in[4];
    const float* b1    = (const float*)d_in[5];
    const float* W2    = (const float*)d_in[6];
    const float* b2    = (const float*)d_in[7];

    float* out    = (float*)d_out;
    float* adj    = out;
    float* out_mu = out + (size_t)NN * NN;
    float* out_lv = out_mu + (size_t)NN * HD2;

    float*  ws    = (float*)d_ws;
    float*  dis   = ws;                                  // NN f32
    float*  bufA  = ws + NN;                             // NN*HD f32
    ushort* xhl   = (ushort*)(bufA + (size_t)NN * HD);   // NN*1024 ush
    ushort* hhl   = xhl;                                 // reuse after gemm1 (NN*512 ush)
    ushort* zhl   = xhl + (size_t)NN * 512;              // reuse tail (NN*256 ush)
    ushort* wencT = xhl + (size_t)NN * 1024;             // 256*1024 ush
    ushort* wcatT = wencT + 256 * 1024;                  // 256*512 ush
    int2*   ew    = (int2*)(wcatT + 256 * 512);          // NE int2
    int*    icnt  = (int*)(ew + NE);                     // NN
    int*    off   = icnt + NN;                           // NN+1
    int*    cur   = off + NN + 1;                        // NN

    // CSR build
    hipMemsetAsync(icnt, 0, NN * sizeof(int), stream);
    hipMemsetAsync(cur, 0, NN * sizeof(int), stream);
    count_deg_kernel<<<NE / 256, 256, 0, stream>>>(ei + NE, icnt, NE);
    finish_dis_kernel<<<NN / 256, 256, 0, stream>>>(icnt, dis, NN);
    scan_kernel<<<1, 256, 0, stream>>>(icnt, off);
    fill_kernel<<<NE / 256, 256, 0, stream>>>(ei, off, cur, dis, ew, NE);

    // hi/lo conversions
    conv_x_kernel<<<NN * 64 / 256, 256, 0, stream>>>(x, xhl);
    conv_w_kernel<<<64, 256, 0, stream>>>(W_enc, nullptr, wencT, FIN, 6);
    conv_w_kernel<<<32, 256, 0, stream>>>(W1, W2, wcatT, HD, 5);

    // layer 1: XW (MFMA) -> gather+relu -> h_hl
    hl_gemm_kernel<<<dim3(2, NN / 128), 256, 0, stream>>>(xhl, wencT, bufA, FIN / 64);
    gather0_kernel<<<NN * 64 / 256, 256, 0, stream>>>(off, ew, dis, bufA, b_enc, hhl);

    // layer 2: HW (MFMA) -> gather -> mu/logvar + z_hl
    hl_gemm_kernel<<<dim3(2, NN / 128), 256, 0, stream>>>(hhl, wcatT, bufA, HD / 64);
    gather1_kernel<<<NN * 64 / 256, 256, 0, stream>>>(off, ew, dis, bufA, b1, b2,
                                                      out_mu, out_lv, zhl);

    // Adj = z z^T (1D triangular grid + mirror)
    zz_tri_kernel<<<NB * (NB + 1) / 2, 256, 0, stream>>>(zhl, adj);
}

// Round 8
// 492.210 us; speedup vs baseline: 1.1726x; 1.0120x over previous
//
#include <hip/hip_runtime.h>
#include <hip/hip_bf16.h>

#define NN 16384
#define NE 524288
#define FIN 512
#define HD 256
#define HD2 128
#define NB 128  // NN/128 tile blocks per dim

typedef __attribute__((ext_vector_type(8))) short bfrag;   // 8 bf16 = 4 VGPRs
typedef __attribute__((ext_vector_type(4))) float ffrag;   // 4 f32 acc

union U8 { ushort u[8]; uint4 v; };

static __device__ __forceinline__ ushort f2bf(float f) {
    uint u = __float_as_uint(f);
    return (ushort)((u + 0x7fff + ((u >> 16) & 1)) >> 16);  // RNE
}
static __device__ __forceinline__ float bf2f(ushort h) {
    return __uint_as_float(((uint)h) << 16);
}

// ---------------- CSR build ----------------
__global__ __launch_bounds__(256) void count_deg_kernel(const int* __restrict__ col,
                                                        int* __restrict__ cnt, int E) {
    int e = blockIdx.x * blockDim.x + threadIdx.x;
    if (e < E) atomicAdd(&cnt[col[e]], 1);
}

// exclusive scan of counts + dis = rsqrt(cnt+1) fused
__global__ __launch_bounds__(256) void scan_kernel(const int* __restrict__ cnt,
                                                   int* __restrict__ off,
                                                   float* __restrict__ dis) {
    __shared__ int part[256];
    const int t = threadIdx.x;
    const int base = t * 64;
    int s = 0;
#pragma unroll 4
    for (int j = 0; j < 64; ++j) s += cnt[base + j];
    part[t] = s;
    __syncthreads();
    for (int d = 1; d < 256; d <<= 1) {
        int v = (t >= d) ? part[t - d] : 0;
        __syncthreads();
        part[t] += v;
        __syncthreads();
    }
    int run = (t == 0) ? 0 : part[t - 1];
    for (int j = 0; j < 64; ++j) {
        const int cv = cnt[base + j];
        off[base + j] = run;
        run += cv;
        dis[base + j] = rsqrtf((float)cv + 1.0f);
    }
    if (t == 255) off[NN] = run;
}

// pack (src, weight-bits) per edge
__global__ __launch_bounds__(256) void fill_kernel(const int* __restrict__ ei,
                                                   const int* __restrict__ off,
                                                   int* __restrict__ cur,
                                                   const float* __restrict__ dis,
                                                   int2* __restrict__ ew, int E) {
    int e = blockIdx.x * blockDim.x + threadIdx.x;
    if (e >= E) return;
    int r = ei[e], c = ei[E + e];
    int pos = off[c] + atomicAdd(&cur[c], 1);
    int2 p; p.x = r; p.y = __float_as_int(dis[r]);
    ew[pos] = p;
}

// ---------------- fused hi/lo bf16 conversions (x, Wenc^T, Wcat^T in one launch) ----
// Row layout, K feats: K/64 segments x 128 ush; seg = [8 hi chunks | 8 lo chunks],
// chunk of 8 feats, stored chunk = c ^ (row & 7).
__global__ __launch_bounds__(256) void conv_all_kernel(const float* __restrict__ x,
                                                       const float* __restrict__ W_enc,
                                                       const float* __restrict__ W1,
                                                       const float* __restrict__ W2,
                                                       ushort* __restrict__ xhl,
                                                       ushort* __restrict__ wencT,
                                                       ushort* __restrict__ wcatT) {
    const int b = blockIdx.x, tid = threadIdx.x;
    U8 hi, lo;
    if (b < 4096) {  // x path: NN*64 chunk-tasks
        const int t = b * 256 + tid;
        const int r = t >> 6, ci = t & 63;
        const int seg = ci >> 3, c = ci & 7;
        const float* src = x + (size_t)r * FIN + ci * 8;
#pragma unroll
        for (int u = 0; u < 8; ++u) {
            float v = src[u];
            ushort h = f2bf(v);
            hi.u[u] = h;
            lo.u[u] = f2bf(v - bf2f(h));
        }
        ushort* dst = xhl + (size_t)r * (FIN * 2) + seg * 128 + ((c ^ (r & 7)) * 8);
        *(uint4*)dst = hi.v;
        *(uint4*)(dst + 64) = lo.v;
    } else if (b < 4160) {  // Wenc^T: 256 out-rows x 64 chunks
        const int t = (b - 4096) * 256 + tid;
        const int n = t >> 6, ci = t & 63;
        const int seg = ci >> 3, c = ci & 7;
#pragma unroll
        for (int u = 0; u < 8; ++u) {
            float v = W_enc[(size_t)(ci * 8 + u) * HD + n];
            ushort h = f2bf(v);
            hi.u[u] = h;
            lo.u[u] = f2bf(v - bf2f(h));
        }
        ushort* dst = wencT + (size_t)n * (FIN * 2) + seg * 128 + ((c ^ (n & 7)) * 8);
        *(uint4*)dst = hi.v;
        *(uint4*)(dst + 64) = lo.v;
    } else {  // Wcat^T = [W1|W2]^T: 256 out-rows x 32 chunks
        const int t = (b - 4160) * 256 + tid;
        const int n = t >> 5, ci = t & 31;
        const int seg = ci >> 3, c = ci & 7;
#pragma unroll
        for (int u = 0; u < 8; ++u) {
            const int k = ci * 8 + u;
            float v = (n < HD2) ? W1[(size_t)k * HD2 + n] : W2[(size_t)k * HD2 + (n - HD2)];
            ushort h = f2bf(v);
            hi.u[u] = h;
            lo.u[u] = f2bf(v - bf2f(h));
        }
        ushort* dst = wcatT + (size_t)n * (HD * 2) + seg * 128 + ((c ^ (n & 7)) * 8);
        *(uint4*)dst = hi.v;
        *(uint4*)(dst + 64) = lo.v;
    }
}

// ---------------- generic hi/lo GEMM (3-product): C[M][256] = Ahl . Bhl^T ----------------
__global__ __launch_bounds__(256, 2) void hl_gemm_kernel(const ushort* __restrict__ A,
                                                         const ushort* __restrict__ B,
                                                         float* __restrict__ C,
                                                         int nseg) {
    __shared__ ushort Ash[128 * 128];
    __shared__ ushort Bsh[128 * 128];
    const int tid = threadIdx.x;
    const int lane = tid & 63, wid = tid >> 6;
    const int rA0 = blockIdx.y * 128, cB0 = blockIdx.x * 128;
    const int rowush = nseg * 128;
    const int wm = (wid >> 1) * 64, wn = (wid & 1) * 64;
    const int fr = lane & 15, g = lane >> 4;

    ffrag acc[4][4];
#pragma unroll
    for (int i = 0; i < 4; ++i)
#pragma unroll
        for (int j = 0; j < 4; ++j) acc[i][j] = (ffrag){0.f, 0.f, 0.f, 0.f};

    for (int s = 0; s < nseg; ++s) {
        if (s) __syncthreads();
#pragma unroll
        for (int it = 0; it < 8; ++it) {
            int idx = it * 256 + tid;
            int row = idx >> 4, c16 = idx & 15;
            *(uint4*)&Ash[idx * 8] = *(const uint4*)&A[(size_t)(rA0 + row) * rowush + s * 128 + c16 * 8];
            *(uint4*)&Bsh[idx * 8] = *(const uint4*)&B[(size_t)(cB0 + row) * rowush + s * 128 + c16 * 8];
        }
        __syncthreads();
#pragma unroll
        for (int m = 0; m < 2; ++m) {
            bfrag ah[4], al[4], bh[4], bl[4];
            const int sw = ((m * 4 + g) ^ (fr & 7)) * 8;
#pragma unroll
            for (int mf = 0; mf < 4; ++mf) {
                const int base = (wm + mf * 16 + fr) * 128;
                ah[mf] = *(const bfrag*)&Ash[base + sw];
                al[mf] = *(const bfrag*)&Ash[base + 64 + sw];
            }
#pragma unroll
            for (int nf = 0; nf < 4; ++nf) {
                const int base = (wn + nf * 16 + fr) * 128;
                bh[nf] = *(const bfrag*)&Bsh[base + sw];
                bl[nf] = *(const bfrag*)&Bsh[base + 64 + sw];
            }
#pragma unroll
            for (int mf = 0; mf < 4; ++mf)
#pragma unroll
                for (int nf = 0; nf < 4; ++nf) {
                    acc[mf][nf] = __builtin_amdgcn_mfma_f32_16x16x32_bf16(ah[mf], bh[nf], acc[mf][nf], 0, 0, 0);
                    acc[mf][nf] = __builtin_amdgcn_mfma_f32_16x16x32_bf16(ah[mf], bl[nf], acc[mf][nf], 0, 0, 0);
                    acc[mf][nf] = __builtin_amdgcn_mfma_f32_16x16x32_bf16(al[mf], bh[nf], acc[mf][nf], 0, 0, 0);
                }
        }
    }
    const size_t row0 = (size_t)rA0 + wm;
    const int col0 = cB0 + wn;
#pragma unroll
    for (int mf = 0; mf < 4; ++mf)
#pragma unroll
        for (int reg = 0; reg < 4; ++reg) {
            float* outp = C + (row0 + mf * 16 + g * 4 + reg) * HD + col0 + fr;
#pragma unroll
            for (int nf = 0; nf < 4; ++nf) outp[nf * 16] = acc[mf][nf][reg];
        }
}

// ---------------- gather layer 1: relu(bias + norm-agg) -> h_hl ----------------
// scalar (s_load) CSR stream via readfirstlane; 4-deep unrolled row gather
__global__ __launch_bounds__(256) void gather0_kernel(const int* __restrict__ off,
                                                      const int2* __restrict__ ew,
                                                      const float* __restrict__ dis,
                                                      const float* __restrict__ A,
                                                      const float* __restrict__ bias,
                                                      ushort* __restrict__ hhl) {
    const int i = __builtin_amdgcn_readfirstlane((blockIdx.x * blockDim.x + threadIdx.x) >> 6);
    const int lane = threadIdx.x & 63;
    const float di = dis[i];
    const int j = lane * 4;
    float4 a0 = *(const float4*)&A[(size_t)i * HD + j];
    a0.x *= di; a0.y *= di; a0.z *= di; a0.w *= di;
    float4 s1 = make_float4(0.f, 0.f, 0.f, 0.f);
    float4 s2 = make_float4(0.f, 0.f, 0.f, 0.f);
    float4 s3 = make_float4(0.f, 0.f, 0.f, 0.f);
    const int k1 = off[i + 1];
    int k = off[i];
    for (; k + 4 <= k1; k += 4) {
        const int2 e0 = ew[k], e1 = ew[k + 1], e2 = ew[k + 2], e3 = ew[k + 3];
        const float w0 = __int_as_float(e0.y), w1 = __int_as_float(e1.y);
        const float w2 = __int_as_float(e2.y), w3 = __int_as_float(e3.y);
        const float4 v0 = *(const float4*)&A[(size_t)e0.x * HD + j];
        const float4 v1 = *(const float4*)&A[(size_t)e1.x * HD + j];
        const float4 v2 = *(const float4*)&A[(size_t)e2.x * HD + j];
        const float4 v3 = *(const float4*)&A[(size_t)e3.x * HD + j];
        a0.x += w0 * v0.x; a0.y += w0 * v0.y; a0.z += w0 * v0.z; a0.w += w0 * v0.w;
        s1.x += w1 * v1.x; s1.y += w1 * v1.y; s1.z += w1 * v1.z; s1.w += w1 * v1.w;
        s2.x += w2 * v2.x; s2.y += w2 * v2.y; s2.z += w2 * v2.z; s2.w += w2 * v2.w;
        s3.x += w3 * v3.x; s3.y += w3 * v3.y; s3.z += w3 * v3.z; s3.w += w3 * v3.w;
    }
    for (; k < k1; ++k) {
        const int2 e0 = ew[k];
        const float w0 = __int_as_float(e0.y);
        const float4 v0 = *(const float4*)&A[(size_t)e0.x * HD + j];
        a0.x += w0 * v0.x; a0.y += w0 * v0.y; a0.z += w0 * v0.z; a0.w += w0 * v0.w;
    }
    a0.x += s1.x + s2.x + s3.x;
    a0.y += s1.y + s2.y + s3.y;
    a0.z += s1.z + s2.z + s3.z;
    a0.w += s1.w + s2.w + s3.w;
    const float4 bb = *(const float4*)&bias[j];
    a0.x = fmaxf(a0.x * di + bb.x, 0.f);
    a0.y = fmaxf(a0.y * di + bb.y, 0.f);
    a0.z = fmaxf(a0.z * di + bb.z, 0.f);
    a0.w = fmaxf(a0.w * di + bb.w, 0.f);
    ushort4 hv, lv;
    hv.x = f2bf(a0.x); lv.x = f2bf(a0.x - bf2f(hv.x));
    hv.y = f2bf(a0.y); lv.y = f2bf(a0.y - bf2f(hv.y));
    hv.z = f2bf(a0.z); lv.z = f2bf(a0.z - bf2f(hv.z));
    hv.w = f2bf(a0.w); lv.w = f2bf(a0.w - bf2f(hv.w));
    const int seg = lane >> 4, c = (lane >> 1) & 7, half = (lane & 1) * 4;
    ushort* dst = hhl + (size_t)i * (HD * 2) + seg * 128 + ((c ^ (i & 7)) * 8) + half;
    *(ushort4*)dst = hv;
    *(ushort4*)(dst + 64) = lv;
}

// ---------------- gather layer 2: mu/logvar f32 out + z_hl ----------------
__global__ __launch_bounds__(256) void gather1_kernel(const int* __restrict__ off,
                                                      const int2* __restrict__ ew,
                                                      const float* __restrict__ dis,
                                                      const float* __restrict__ A,
                                                      const float* __restrict__ b1,
                                                      const float* __restrict__ b2,
                                                      float* __restrict__ out_mu,
                                                      float* __restrict__ out_lv,
                                                      ushort* __restrict__ zhl) {
    const int i = __builtin_amdgcn_readfirstlane((blockIdx.x * blockDim.x + threadIdx.x) >> 6);
    const int lane = threadIdx.x & 63;
    const float di = dis[i];
    const int j = lane * 4;
    float4 a0 = *(const float4*)&A[(size_t)i * HD + j];
    a0.x *= di; a0.y *= di; a0.z *= di; a0.w *= di;
    float4 s1 = make_float4(0.f, 0.f, 0.f, 0.f);
    float4 s2 = make_float4(0.f, 0.f, 0.f, 0.f);
    float4 s3 = make_float4(0.f, 0.f, 0.f, 0.f);
    const int k1 = off[i + 1];
    int k = off[i];
    for (; k + 4 <= k1; k += 4) {
        const int2 e0 = ew[k], e1 = ew[k + 1], e2 = ew[k + 2], e3 = ew[k + 3];
        const float w0 = __int_as_float(e0.y), w1 = __int_as_float(e1.y);
        const float w2 = __int_as_float(e2.y), w3 = __int_as_float(e3.y);
        const float4 v0 = *(const float4*)&A[(size_t)e0.x * HD + j];
        const float4 v1 = *(const float4*)&A[(size_t)e1.x * HD + j];
        const float4 v2 = *(const float4*)&A[(size_t)e2.x * HD + j];
        const float4 v3 = *(const float4*)&A[(size_t)e3.x * HD + j];
        a0.x += w0 * v0.x; a0.y += w0 * v0.y; a0.z += w0 * v0.z; a0.w += w0 * v0.w;
        s1.x += w1 * v1.x; s1.y += w1 * v1.y; s1.z += w1 * v1.z; s1.w += w1 * v1.w;
        s2.x += w2 * v2.x; s2.y += w2 * v2.y; s2.z += w2 * v2.z; s2.w += w2 * v2.w;
        s3.x += w3 * v3.x; s3.y += w3 * v3.y; s3.z += w3 * v3.z; s3.w += w3 * v3.w;
    }
    for (; k < k1; ++k) {
        const int2 e0 = ew[k];
        const float w0 = __int_as_float(e0.y);
        const float4 v0 = *(const float4*)&A[(size_t)e0.x * HD + j];
        a0.x += w0 * v0.x; a0.y += w0 * v0.y; a0.z += w0 * v0.z; a0.w += w0 * v0.w;
    }
    float4 r;
    r.x = (a0.x + s1.x + s2.x + s3.x) * di;
    r.y = (a0.y + s1.y + s2.y + s3.y) * di;
    r.z = (a0.z + s1.z + s2.z + s3.z) * di;
    r.w = (a0.w + s1.w + s2.w + s3.w) * di;
    if (lane < 32) {
        const float4 bb = *(const float4*)&b1[j];
        r.x += bb.x; r.y += bb.y; r.z += bb.z; r.w += bb.w;
        *(float4*)&out_mu[(size_t)i * HD2 + j] = r;
        ushort4 hv, lv;
        hv.x = f2bf(r.x); lv.x = f2bf(r.x - bf2f(hv.x));
        hv.y = f2bf(r.y); lv.y = f2bf(r.y - bf2f(hv.y));
        hv.z = f2bf(r.z); lv.z = f2bf(r.z - bf2f(hv.z));
        hv.w = f2bf(r.w); lv.w = f2bf(r.w - bf2f(hv.w));
        const int seg = lane >> 4, c = (lane >> 1) & 7, half = (lane & 1) * 4;
        ushort* dst = zhl + (size_t)i * (HD2 * 2) + seg * 128 + ((c ^ (i & 7)) * 8) + half;
        *(ushort4*)dst = hv;
        *(ushort4*)(dst + 64) = lv;
    } else {
        const int jj = j - HD2;
        const float4 bb = *(const float4*)&b2[jj];
        r.x += bb.x; r.y += bb.y; r.z += bb.z; r.w += bb.w;
        *(float4*)&out_lv[(size_t)i * HD2 + jj] = r;
    }
}

// ---------------- Adj = z z^T, 1D triangular grid + mirror, 3-product ----------------
__global__ __launch_bounds__(256, 2) void zz_tri_kernel(const ushort* __restrict__ Z,
                                                        float* __restrict__ adj) {
    // decode linear block id -> (bm, bn), bm <= bn
    const int t = blockIdx.x;
    int bm = (int)((257.0f - sqrtf(66049.0f - 8.0f * (float)t)) * 0.5f);
    while (bm * NB - bm * (bm - 1) / 2 > t) --bm;
    while ((bm + 1) * NB - (bm + 1) * bm / 2 <= t) ++bm;
    const int bn = bm + (t - (bm * NB - bm * (bm - 1) / 2));

    __shared__ ushort Ash[128 * 128];
    __shared__ ushort Bsh[128 * 128];
    const int tid = threadIdx.x;
    const int lane = tid & 63, wid = tid >> 6;
    const int wm = (wid >> 1) * 64, wn = (wid & 1) * 64;
    const int fr = lane & 15, g = lane >> 4;

    ffrag acc[4][4];
#pragma unroll
    for (int i = 0; i < 4; ++i)
#pragma unroll
        for (int j = 0; j < 4; ++j) acc[i][j] = (ffrag){0.f, 0.f, 0.f, 0.f};

#pragma unroll
    for (int s = 0; s < 2; ++s) {
        if (s) __syncthreads();
#pragma unroll
        for (int it = 0; it < 8; ++it) {
            int idx = it * 256 + tid;
            int row = idx >> 4, c16 = idx & 15;
            *(uint4*)&Ash[idx * 8] = *(const uint4*)&Z[(size_t)(bm * 128 + row) * 256 + s * 128 + c16 * 8];
            *(uint4*)&Bsh[idx * 8] = *(const uint4*)&Z[(size_t)(bn * 128 + row) * 256 + s * 128 + c16 * 8];
        }
        __syncthreads();
#pragma unroll
        for (int m = 0; m < 2; ++m) {
            bfrag ah[4], al[4], bh[4], bl[4];
            const int sw = ((m * 4 + g) ^ (fr & 7)) * 8;
#pragma unroll
            for (int mf = 0; mf < 4; ++mf) {
                const int base = (wm + mf * 16 + fr) * 128;
                ah[mf] = *(const bfrag*)&Ash[base + sw];
                al[mf] = *(const bfrag*)&Ash[base + 64 + sw];
            }
#pragma unroll
            for (int nf = 0; nf < 4; ++nf) {
                const int base = (wn + nf * 16 + fr) * 128;
                bh[nf] = *(const bfrag*)&Bsh[base + sw];
                bl[nf] = *(const bfrag*)&Bsh[base + 64 + sw];
            }
#pragma unroll
            for (int mf = 0; mf < 4; ++mf)
#pragma unroll
                for (int nf = 0; nf < 4; ++nf) {
                    acc[mf][nf] = __builtin_amdgcn_mfma_f32_16x16x32_bf16(ah[mf], bh[nf], acc[mf][nf], 0, 0, 0);
                    acc[mf][nf] = __builtin_amdgcn_mfma_f32_16x16x32_bf16(ah[mf], bl[nf], acc[mf][nf], 0, 0, 0);
                    acc[mf][nf] = __builtin_amdgcn_mfma_f32_16x16x32_bf16(al[mf], bh[nf], acc[mf][nf], 0, 0, 0);
                }
        }
    }

    // normal store (upper tile), cached
    const size_t row0 = (size_t)bm * 128 + wm;
    const int col0 = bn * 128 + wn;
#pragma unroll
    for (int mf = 0; mf < 4; ++mf)
#pragma unroll
        for (int reg = 0; reg < 4; ++reg) {
            float* outp = adj + (row0 + mf * 16 + g * 4 + reg) * NN + col0 + fr;
#pragma unroll
            for (int nf = 0; nf < 4; ++nf) outp[nf * 16] = acc[mf][nf][reg];
        }
    // mirror store (lower tile): the 4 regs are 4 consecutive cols -> float4 store
    if (bm != bn) {
#pragma unroll
        for (int nf = 0; nf < 4; ++nf)
#pragma unroll
            for (int mf = 0; mf < 4; ++mf) {
                const size_t addr = ((size_t)bn * 128 + wn + nf * 16 + fr) * NN
                                  + (size_t)bm * 128 + wm + mf * 16 + g * 4;
                *(float4*)&adj[addr] = *(float4*)&acc[mf][nf];
            }
    }
}

extern "C" void kernel_launch(void* const* d_in, const int* in_sizes, int n_in,
                              void* d_out, int out_size, void* d_ws, size_t ws_size,
                              hipStream_t stream) {
    const float* x     = (const float*)d_in[0];
    const int*   ei    = (const int*)d_in[1];
    const float* W_enc = (const float*)d_in[2];
    const float* b_enc = (const float*)d_in[3];
    const float* W1    = (const float*)d_in[4];
    const float* b1    = (const float*)d_in[5];
    const float* W2    = (const float*)d_in[6];
    const float* b2    = (const float*)d_in[7];

    float* out    = (float*)d_out;
    float* adj    = out;
    float* out_mu = out + (size_t)NN * NN;
    float* out_lv = out_mu + (size_t)NN * HD2;

    float*  ws    = (float*)d_ws;
    float*  dis   = ws;                                  // NN f32
    float*  bufA  = ws + NN;                             // NN*HD f32
    ushort* xhl   = (ushort*)(bufA + (size_t)NN * HD);   // NN*1024 ush
    ushort* hhl   = xhl;                                 // reuse after gemm1 (NN*512 ush)
    ushort* zhl   = xhl + (size_t)NN * 512;              // reuse tail (NN*256 ush)
    ushort* wencT = xhl + (size_t)NN * 1024;             // 256*1024 ush
    ushort* wcatT = wencT + 256 * 1024;                  // 256*512 ush
    int2*   ew    = (int2*)(wcatT + 256 * 512);          // NE int2
    int*    icnt  = (int*)(ew + NE);                     // NN
    int*    off   = icnt + NN;                           // NN+1
    int*    cur   = off + NN + 1;                        // NN

    // CSR build
    hipMemsetAsync(icnt, 0, NN * sizeof(int), stream);
    hipMemsetAsync(cur, 0, NN * sizeof(int), stream);
    count_deg_kernel<<<NE / 256, 256, 0, stream>>>(ei + NE, icnt, NE);
    scan_kernel<<<1, 256, 0, stream>>>(icnt, off, dis);
    fill_kernel<<<NE / 256, 256, 0, stream>>>(ei, off, cur, dis, ew, NE);

    // hi/lo conversions (x + both weights, one launch)
    conv_all_kernel<<<4192, 256, 0, stream>>>(x, W_enc, W1, W2, xhl, wencT, wcatT);

    // layer 1: XW (MFMA) -> gather+relu -> h_hl
    hl_gemm_kernel<<<dim3(2, NN / 128), 256, 0, stream>>>(xhl, wencT, bufA, FIN / 64);
    gather0_kernel<<<NN * 64 / 256, 256, 0, stream>>>(off, ew, dis, bufA, b_enc, hhl);

    // layer 2: HW (MFMA) -> gather -> mu/logvar + z_hl
    hl_gemm_kernel<<<dim3(2, NN / 128), 256, 0, stream>>>(hhl, wcatT, bufA, HD / 64);
    gather1_kernel<<<NN * 64 / 256, 256, 0, stream>>>(off, ew, dis, bufA, b1, b2,
                                                      out_mu, out_lv, zhl);

    // Adj = z z^T (1D triangular grid + mirror)
    zz_tri_kernel<<<NB * (NB + 1) / 2, 256, 0, stream>>>(zhl, adj);
}

// Round 9
// 491.804 us; speedup vs baseline: 1.1735x; 1.0008x over previous
//
#include <hip/hip_runtime.h>
#include <hip/hip_bf16.h>

#define NN 16384
#define NE 524288
#define FIN 512
#define HD 256
#define HD2 128
#define NB 128          // NN/128 tile blocks per dim
#define NTRI (NB * (NB + 1) / 2)   // 8256
#define NCHUNK (NTRI / 8)          // 1032 (exact)

typedef __attribute__((ext_vector_type(8))) short bfrag;   // 8 bf16 = 4 VGPRs
typedef __attribute__((ext_vector_type(4))) float ffrag;   // 4 f32 acc

union U8 { ushort u[8]; uint4 v; };

static __device__ __forceinline__ ushort f2bf(float f) {
    uint u = __float_as_uint(f);
    return (ushort)((u + 0x7fff + ((u >> 16) & 1)) >> 16);  // RNE
}
static __device__ __forceinline__ float bf2f(ushort h) {
    return __uint_as_float(((uint)h) << 16);
}

// ---------------- fused: edge-degree count + hi/lo conversions ----------------
// b < 2048            : count_deg over edges
// 2048 <= b < 6144    : x -> xhl
// 6144 <= b < 6208    : Wenc^T -> wencT
// 6208 <= b < 6240    : [W1|W2]^T -> wcatT
__global__ __launch_bounds__(256) void pre_kernel(const int* __restrict__ col,
                                                  int* __restrict__ cnt,
                                                  const float* __restrict__ x,
                                                  const float* __restrict__ W_enc,
                                                  const float* __restrict__ W1,
                                                  const float* __restrict__ W2,
                                                  ushort* __restrict__ xhl,
                                                  ushort* __restrict__ wencT,
                                                  ushort* __restrict__ wcatT) {
    const int b = blockIdx.x, tid = threadIdx.x;
    if (b < 2048) {
        atomicAdd(&cnt[col[b * 256 + tid]], 1);
        return;
    }
    U8 hi, lo;
    if (b < 6144) {  // x path: NN*64 chunk-tasks
        const int t = (b - 2048) * 256 + tid;
        const int r = t >> 6, ci = t & 63;
        const int seg = ci >> 3, c = ci & 7;
        const float* src = x + (size_t)r * FIN + ci * 8;
#pragma unroll
        for (int u = 0; u < 8; ++u) {
            float v = src[u];
            ushort h = f2bf(v);
            hi.u[u] = h;
            lo.u[u] = f2bf(v - bf2f(h));
        }
        ushort* dst = xhl + (size_t)r * (FIN * 2) + seg * 128 + ((c ^ (r & 7)) * 8);
        *(uint4*)dst = hi.v;
        *(uint4*)(dst + 64) = lo.v;
    } else if (b < 6208) {  // Wenc^T: 256 out-rows x 64 chunks
        const int t = (b - 6144) * 256 + tid;
        const int n = t >> 6, ci = t & 63;
        const int seg = ci >> 3, c = ci & 7;
#pragma unroll
        for (int u = 0; u < 8; ++u) {
            float v = W_enc[(size_t)(ci * 8 + u) * HD + n];
            ushort h = f2bf(v);
            hi.u[u] = h;
            lo.u[u] = f2bf(v - bf2f(h));
        }
        ushort* dst = wencT + (size_t)n * (FIN * 2) + seg * 128 + ((c ^ (n & 7)) * 8);
        *(uint4*)dst = hi.v;
        *(uint4*)(dst + 64) = lo.v;
    } else {  // Wcat^T = [W1|W2]^T: 256 out-rows x 32 chunks
        const int t = (b - 6208) * 256 + tid;
        const int n = t >> 5, ci = t & 31;
        const int seg = ci >> 3, c = ci & 7;
#pragma unroll
        for (int u = 0; u < 8; ++u) {
            const int k = ci * 8 + u;
            float v = (n < HD2) ? W1[(size_t)k * HD2 + n] : W2[(size_t)k * HD2 + (n - HD2)];
            ushort h = f2bf(v);
            hi.u[u] = h;
            lo.u[u] = f2bf(v - bf2f(h));
        }
        ushort* dst = wcatT + (size_t)n * (HD * 2) + seg * 128 + ((c ^ (n & 7)) * 8);
        *(uint4*)dst = hi.v;
        *(uint4*)(dst + 64) = lo.v;
    }
}

// exclusive scan of counts + dis = rsqrt(cnt+1) fused
__global__ __launch_bounds__(256) void scan_kernel(const int* __restrict__ cnt,
                                                   int* __restrict__ off,
                                                   float* __restrict__ dis) {
    __shared__ int part[256];
    const int t = threadIdx.x;
    const int base = t * 64;
    int s = 0;
#pragma unroll 4
    for (int j = 0; j < 64; ++j) s += cnt[base + j];
    part[t] = s;
    __syncthreads();
    for (int d = 1; d < 256; d <<= 1) {
        int v = (t >= d) ? part[t - d] : 0;
        __syncthreads();
        part[t] += v;
        __syncthreads();
    }
    int run = (t == 0) ? 0 : part[t - 1];
    for (int j = 0; j < 64; ++j) {
        const int cv = cnt[base + j];
        off[base + j] = run;
        run += cv;
        dis[base + j] = rsqrtf((float)cv + 1.0f);
    }
    if (t == 255) off[NN] = run;
}

// pack (src, weight-bits) per edge
__global__ __launch_bounds__(256) void fill_kernel(const int* __restrict__ ei,
                                                   const int* __restrict__ off,
                                                   int* __restrict__ cur,
                                                   const float* __restrict__ dis,
                                                   int2* __restrict__ ew, int E) {
    int e = blockIdx.x * blockDim.x + threadIdx.x;
    if (e >= E) return;
    int r = ei[e], c = ei[E + e];
    int pos = off[c] + atomicAdd(&cur[c], 1);
    int2 p; p.x = r; p.y = __float_as_int(dis[r]);
    ew[pos] = p;
}

// ---------------- generic hi/lo GEMM (3-product): C[M][256] = Ahl . Bhl^T ----------------
__global__ __launch_bounds__(256, 2) void hl_gemm_kernel(const ushort* __restrict__ A,
                                                         const ushort* __restrict__ B,
                                                         float* __restrict__ C,
                                                         int nseg) {
    __shared__ ushort Ash[128 * 128];
    __shared__ ushort Bsh[128 * 128];
    const int tid = threadIdx.x;
    const int lane = tid & 63, wid = tid >> 6;
    const int rA0 = blockIdx.y * 128, cB0 = blockIdx.x * 128;
    const int rowush = nseg * 128;
    const int wm = (wid >> 1) * 64, wn = (wid & 1) * 64;
    const int fr = lane & 15, g = lane >> 4;

    ffrag acc[4][4];
#pragma unroll
    for (int i = 0; i < 4; ++i)
#pragma unroll
        for (int j = 0; j < 4; ++j) acc[i][j] = (ffrag){0.f, 0.f, 0.f, 0.f};

    for (int s = 0; s < nseg; ++s) {
        if (s) __syncthreads();
#pragma unroll
        for (int it = 0; it < 8; ++it) {
            int idx = it * 256 + tid;
            int row = idx >> 4, c16 = idx & 15;
            *(uint4*)&Ash[idx * 8] = *(const uint4*)&A[(size_t)(rA0 + row) * rowush + s * 128 + c16 * 8];
            *(uint4*)&Bsh[idx * 8] = *(const uint4*)&B[(size_t)(cB0 + row) * rowush + s * 128 + c16 * 8];
        }
        __syncthreads();
#pragma unroll
        for (int m = 0; m < 2; ++m) {
            bfrag ah[4], al[4], bh[4], bl[4];
            const int sw = ((m * 4 + g) ^ (fr & 7)) * 8;
#pragma unroll
            for (int mf = 0; mf < 4; ++mf) {
                const int base = (wm + mf * 16 + fr) * 128;
                ah[mf] = *(const bfrag*)&Ash[base + sw];
                al[mf] = *(const bfrag*)&Ash[base + 64 + sw];
            }
#pragma unroll
            for (int nf = 0; nf < 4; ++nf) {
                const int base = (wn + nf * 16 + fr) * 128;
                bh[nf] = *(const bfrag*)&Bsh[base + sw];
                bl[nf] = *(const bfrag*)&Bsh[base + 64 + sw];
            }
#pragma unroll
            for (int mf = 0; mf < 4; ++mf)
#pragma unroll
                for (int nf = 0; nf < 4; ++nf) {
                    acc[mf][nf] = __builtin_amdgcn_mfma_f32_16x16x32_bf16(ah[mf], bh[nf], acc[mf][nf], 0, 0, 0);
                    acc[mf][nf] = __builtin_amdgcn_mfma_f32_16x16x32_bf16(ah[mf], bl[nf], acc[mf][nf], 0, 0, 0);
                    acc[mf][nf] = __builtin_amdgcn_mfma_f32_16x16x32_bf16(al[mf], bh[nf], acc[mf][nf], 0, 0, 0);
                }
        }
    }
    const size_t row0 = (size_t)rA0 + wm;
    const int col0 = cB0 + wn;
#pragma unroll
    for (int mf = 0; mf < 4; ++mf)
#pragma unroll
        for (int reg = 0; reg < 4; ++reg) {
            float* outp = C + (row0 + mf * 16 + g * 4 + reg) * HD + col0 + fr;
#pragma unroll
            for (int nf = 0; nf < 4; ++nf) outp[nf * 16] = acc[mf][nf][reg];
        }
}

// ---------------- gather layer 1: relu(bias + norm-agg) -> h_hl ----------------
__global__ __launch_bounds__(256) void gather0_kernel(const int* __restrict__ off,
                                                      const int2* __restrict__ ew,
                                                      const float* __restrict__ dis,
                                                      const float* __restrict__ A,
                                                      const float* __restrict__ bias,
                                                      ushort* __restrict__ hhl) {
    const int i = __builtin_amdgcn_readfirstlane((blockIdx.x * blockDim.x + threadIdx.x) >> 6);
    const int lane = threadIdx.x & 63;
    const float di = dis[i];
    const int j = lane * 4;
    float4 a0 = *(const float4*)&A[(size_t)i * HD + j];
    a0.x *= di; a0.y *= di; a0.z *= di; a0.w *= di;
    float4 s1 = make_float4(0.f, 0.f, 0.f, 0.f);
    float4 s2 = make_float4(0.f, 0.f, 0.f, 0.f);
    float4 s3 = make_float4(0.f, 0.f, 0.f, 0.f);
    const int k1 = off[i + 1];
    int k = off[i];
    for (; k + 4 <= k1; k += 4) {
        const int2 e0 = ew[k], e1 = ew[k + 1], e2 = ew[k + 2], e3 = ew[k + 3];
        const float w0 = __int_as_float(e0.y), w1 = __int_as_float(e1.y);
        const float w2 = __int_as_float(e2.y), w3 = __int_as_float(e3.y);
        const float4 v0 = *(const float4*)&A[(size_t)e0.x * HD + j];
        const float4 v1 = *(const float4*)&A[(size_t)e1.x * HD + j];
        const float4 v2 = *(const float4*)&A[(size_t)e2.x * HD + j];
        const float4 v3 = *(const float4*)&A[(size_t)e3.x * HD + j];
        a0.x += w0 * v0.x; a0.y += w0 * v0.y; a0.z += w0 * v0.z; a0.w += w0 * v0.w;
        s1.x += w1 * v1.x; s1.y += w1 * v1.y; s1.z += w1 * v1.z; s1.w += w1 * v1.w;
        s2.x += w2 * v2.x; s2.y += w2 * v2.y; s2.z += w2 * v2.z; s2.w += w2 * v2.w;
        s3.x += w3 * v3.x; s3.y += w3 * v3.y; s3.z += w3 * v3.z; s3.w += w3 * v3.w;
    }
    for (; k < k1; ++k) {
        const int2 e0 = ew[k];
        const float w0 = __int_as_float(e0.y);
        const float4 v0 = *(const float4*)&A[(size_t)e0.x * HD + j];
        a0.x += w0 * v0.x; a0.y += w0 * v0.y; a0.z += w0 * v0.z; a0.w += w0 * v0.w;
    }
    a0.x += s1.x + s2.x + s3.x;
    a0.y += s1.y + s2.y + s3.y;
    a0.z += s1.z + s2.z + s3.z;
    a0.w += s1.w + s2.w + s3.w;
    const float4 bb = *(const float4*)&bias[j];
    a0.x = fmaxf(a0.x * di + bb.x, 0.f);
    a0.y = fmaxf(a0.y * di + bb.y, 0.f);
    a0.z = fmaxf(a0.z * di + bb.z, 0.f);
    a0.w = fmaxf(a0.w * di + bb.w, 0.f);
    ushort4 hv, lv;
    hv.x = f2bf(a0.x); lv.x = f2bf(a0.x - bf2f(hv.x));
    hv.y = f2bf(a0.y); lv.y = f2bf(a0.y - bf2f(hv.y));
    hv.z = f2bf(a0.z); lv.z = f2bf(a0.z - bf2f(hv.z));
    hv.w = f2bf(a0.w); lv.w = f2bf(a0.w - bf2f(hv.w));
    const int seg = lane >> 4, c = (lane >> 1) & 7, half = (lane & 1) * 4;
    ushort* dst = hhl + (size_t)i * (HD * 2) + seg * 128 + ((c ^ (i & 7)) * 8) + half;
    *(ushort4*)dst = hv;
    *(ushort4*)(dst + 64) = lv;
}

// ---------------- gather layer 2: mu/logvar f32 out + z_hl ----------------
__global__ __launch_bounds__(256) void gather1_kernel(const int* __restrict__ off,
                                                      const int2* __restrict__ ew,
                                                      const float* __restrict__ dis,
                                                      const float* __restrict__ A,
                                                      const float* __restrict__ b1,
                                                      const float* __restrict__ b2,
                                                      float* __restrict__ out_mu,
                                                      float* __restrict__ out_lv,
                                                      ushort* __restrict__ zhl) {
    const int i = __builtin_amdgcn_readfirstlane((blockIdx.x * blockDim.x + threadIdx.x) >> 6);
    const int lane = threadIdx.x & 63;
    const float di = dis[i];
    const int j = lane * 4;
    float4 a0 = *(const float4*)&A[(size_t)i * HD + j];
    a0.x *= di; a0.y *= di; a0.z *= di; a0.w *= di;
    float4 s1 = make_float4(0.f, 0.f, 0.f, 0.f);
    float4 s2 = make_float4(0.f, 0.f, 0.f, 0.f);
    float4 s3 = make_float4(0.f, 0.f, 0.f, 0.f);
    const int k1 = off[i + 1];
    int k = off[i];
    for (; k + 4 <= k1; k += 4) {
        const int2 e0 = ew[k], e1 = ew[k + 1], e2 = ew[k + 2], e3 = ew[k + 3];
        const float w0 = __int_as_float(e0.y), w1 = __int_as_float(e1.y);
        const float w2 = __int_as_float(e2.y), w3 = __int_as_float(e3.y);
        const float4 v0 = *(const float4*)&A[(size_t)e0.x * HD + j];
        const float4 v1 = *(const float4*)&A[(size_t)e1.x * HD + j];
        const float4 v2 = *(const float4*)&A[(size_t)e2.x * HD + j];
        const float4 v3 = *(const float4*)&A[(size_t)e3.x * HD + j];
        a0.x += w0 * v0.x; a0.y += w0 * v0.y; a0.z += w0 * v0.z; a0.w += w0 * v0.w;
        s1.x += w1 * v1.x; s1.y += w1 * v1.y; s1.z += w1 * v1.z; s1.w += w1 * v1.w;
        s2.x += w2 * v2.x; s2.y += w2 * v2.y; s2.z += w2 * v2.z; s2.w += w2 * v2.w;
        s3.x += w3 * v3.x; s3.y += w3 * v3.y; s3.z += w3 * v3.z; s3.w += w3 * v3.w;
    }
    for (; k < k1; ++k) {
        const int2 e0 = ew[k];
        const float w0 = __int_as_float(e0.y);
        const float4 v0 = *(const float4*)&A[(size_t)e0.x * HD + j];
        a0.x += w0 * v0.x; a0.y += w0 * v0.y; a0.z += w0 * v0.z; a0.w += w0 * v0.w;
    }
    float4 r;
    r.x = (a0.x + s1.x + s2.x + s3.x) * di;
    r.y = (a0.y + s1.y + s2.y + s3.y) * di;
    r.z = (a0.z + s1.z + s2.z + s3.z) * di;
    r.w = (a0.w + s1.w + s2.w + s3.w) * di;
    if (lane < 32) {
        const float4 bb = *(const float4*)&b1[j];
        r.x += bb.x; r.y += bb.y; r.z += bb.z; r.w += bb.w;
        *(float4*)&out_mu[(size_t)i * HD2 + j] = r;
        ushort4 hv, lv;
        hv.x = f2bf(r.x); lv.x = f2bf(r.x - bf2f(hv.x));
        hv.y = f2bf(r.y); lv.y = f2bf(r.y - bf2f(hv.y));
        hv.z = f2bf(r.z); lv.z = f2bf(r.z - bf2f(hv.z));
        hv.w = f2bf(r.w); lv.w = f2bf(r.w - bf2f(hv.w));
        const int seg = lane >> 4, c = (lane >> 1) & 7, half = (lane & 1) * 4;
        ushort* dst = zhl + (size_t)i * (HD2 * 2) + seg * 128 + ((c ^ (i & 7)) * 8) + half;
        *(ushort4*)dst = hv;
        *(ushort4*)(dst + 64) = lv;
    } else {
        const int jj = j - HD2;
        const float4 bb = *(const float4*)&b2[jj];
        r.x += bb.x; r.y += bb.y; r.z += bb.z; r.w += bb.w;
        *(float4*)&out_lv[(size_t)i * HD2 + jj] = r;
    }
}

// ---------------- Adj = z z^T, XCD-swizzled 1D triangular grid + mirror ----------------
__global__ __launch_bounds__(256, 2) void zz_tri_kernel(const ushort* __restrict__ Z,
                                                        float* __restrict__ adj) {
    // XCD-aware remap: XCD k (= orig%8) gets contiguous triangular range
    // [k*NCHUNK, (k+1)*NCHUNK) -> consecutive blocks share bm -> A-tile L2 reuse
    const int orig = blockIdx.x;
    const int t = (orig & 7) * NCHUNK + (orig >> 3);
    // decode linear tri id -> (bm, bn), bm <= bn
    int bm = (int)((257.0f - sqrtf(66049.0f - 8.0f * (float)t)) * 0.5f);
    while (bm * NB - bm * (bm - 1) / 2 > t) --bm;
    while ((bm + 1) * NB - (bm + 1) * bm / 2 <= t) ++bm;
    const int bn = bm + (t - (bm * NB - bm * (bm - 1) / 2));

    __shared__ ushort Ash[128 * 128];
    __shared__ ushort Bsh[128 * 128];
    const int tid = threadIdx.x;
    const int lane = tid & 63, wid = tid >> 6;
    const int wm = (wid >> 1) * 64, wn = (wid & 1) * 64;
    const int fr = lane & 15, g = lane >> 4;

    ffrag acc[4][4];
#pragma unroll
    for (int i = 0; i < 4; ++i)
#pragma unroll
        for (int j = 0; j < 4; ++j) acc[i][j] = (ffrag){0.f, 0.f, 0.f, 0.f};

#pragma unroll
    for (int s = 0; s < 2; ++s) {
        if (s) __syncthreads();
#pragma unroll
        for (int it = 0; it < 8; ++it) {
            int idx = it * 256 + tid;
            int row = idx >> 4, c16 = idx & 15;
            *(uint4*)&Ash[idx * 8] = *(const uint4*)&Z[(size_t)(bm * 128 + row) * 256 + s * 128 + c16 * 8];
            *(uint4*)&Bsh[idx * 8] = *(const uint4*)&Z[(size_t)(bn * 128 + row) * 256 + s * 128 + c16 * 8];
        }
        __syncthreads();
#pragma unroll
        for (int m = 0; m < 2; ++m) {
            bfrag ah[4], al[4], bh[4], bl[4];
            const int sw = ((m * 4 + g) ^ (fr & 7)) * 8;
#pragma unroll
            for (int mf = 0; mf < 4; ++mf) {
                const int base = (wm + mf * 16 + fr) * 128;
                ah[mf] = *(const bfrag*)&Ash[base + sw];
                al[mf] = *(const bfrag*)&Ash[base + 64 + sw];
            }
#pragma unroll
            for (int nf = 0; nf < 4; ++nf) {
                const int base = (wn + nf * 16 + fr) * 128;
                bh[nf] = *(const bfrag*)&Bsh[base + sw];
                bl[nf] = *(const bfrag*)&Bsh[base + 64 + sw];
            }
#pragma unroll
            for (int mf = 0; mf < 4; ++mf)
#pragma unroll
                for (int nf = 0; nf < 4; ++nf) {
                    acc[mf][nf] = __builtin_amdgcn_mfma_f32_16x16x32_bf16(ah[mf], bh[nf], acc[mf][nf], 0, 0, 0);
                    acc[mf][nf] = __builtin_amdgcn_mfma_f32_16x16x32_bf16(ah[mf], bl[nf], acc[mf][nf], 0, 0, 0);
                    acc[mf][nf] = __builtin_amdgcn_mfma_f32_16x16x32_bf16(al[mf], bh[nf], acc[mf][nf], 0, 0, 0);
                }
        }
    }

    // normal store (upper tile), cached
    const size_t row0 = (size_t)bm * 128 + wm;
    const int col0 = bn * 128 + wn;
#pragma unroll
    for (int mf = 0; mf < 4; ++mf)
#pragma unroll
        for (int reg = 0; reg < 4; ++reg) {
            float* outp = adj + (row0 + mf * 16 + g * 4 + reg) * NN + col0 + fr;
#pragma unroll
            for (int nf = 0; nf < 4; ++nf) outp[nf * 16] = acc[mf][nf][reg];
        }
    // mirror store (lower tile): the 4 regs are 4 consecutive cols -> float4 store
    if (bm != bn) {
#pragma unroll
        for (int nf = 0; nf < 4; ++nf)
#pragma unroll
            for (int mf = 0; mf < 4; ++mf) {
                const size_t addr = ((size_t)bn * 128 + wn + nf * 16 + fr) * NN
                                  + (size_t)bm * 128 + wm + mf * 16 + g * 4;
                *(float4*)&adj[addr] = *(float4*)&acc[mf][nf];
            }
    }
}

extern "C" void kernel_launch(void* const* d_in, const int* in_sizes, int n_in,
                              void* d_out, int out_size, void* d_ws, size_t ws_size,
                              hipStream_t stream) {
    const float* x     = (const float*)d_in[0];
    const int*   ei    = (const int*)d_in[1];
    const float* W_enc = (const float*)d_in[2];
    const float* b_enc = (const float*)d_in[3];
    const float* W1    = (const float*)d_in[4];
    const float* b1    = (const float*)d_in[5];
    const float* W2    = (const float*)d_in[6];
    const float* b2    = (const float*)d_in[7];

    float* out    = (float*)d_out;
    float* adj    = out;
    float* out_mu = out + (size_t)NN * NN;
    float* out_lv = out_mu + (size_t)NN * HD2;

    float*  ws    = (float*)d_ws;
    float*  dis   = ws;                                  // NN f32
    float*  bufA  = ws + NN;                             // NN*HD f32
    ushort* xhl   = (ushort*)(bufA + (size_t)NN * HD);   // NN*1024 ush
    ushort* hhl   = xhl;                                 // reuse after gemm1 (NN*512 ush)
    ushort* zhl   = xhl + (size_t)NN * 512;              // reuse tail (NN*256 ush)
    ushort* wencT = xhl + (size_t)NN * 1024;             // 256*1024 ush
    ushort* wcatT = wencT + 256 * 1024;                  // 256*512 ush
    int2*   ew    = (int2*)(wcatT + 256 * 512);          // NE int2
    int*    icnt  = (int*)(ew + NE);                     // NN
    int*    off   = icnt + NN;                           // NN+1
    int*    cur   = off + NN + 1;                        // NN

    // memsets for atomic counters
    hipMemsetAsync(icnt, 0, NN * sizeof(int), stream);
    hipMemsetAsync(cur, 0, NN * sizeof(int), stream);

    // fused: degree count + all hi/lo conversions (independent chains overlap)
    pre_kernel<<<6240, 256, 0, stream>>>(ei + NE, icnt, x, W_enc, W1, W2,
                                         xhl, wencT, wcatT);
    scan_kernel<<<1, 256, 0, stream>>>(icnt, off, dis);
    fill_kernel<<<NE / 256, 256, 0, stream>>>(ei, off, cur, dis, ew, NE);

    // layer 1: XW (MFMA) -> gather+relu -> h_hl
    hl_gemm_kernel<<<dim3(2, NN / 128), 256, 0, stream>>>(xhl, wencT, bufA, FIN / 64);
    gather0_kernel<<<NN * 64 / 256, 256, 0, stream>>>(off, ew, dis, bufA, b_enc, hhl);

    // layer 2: HW (MFMA) -> gather -> mu/logvar + z_hl
    hl_gemm_kernel<<<dim3(2, NN / 128), 256, 0, stream>>>(hhl, wcatT, bufA, HD / 64);
    gather1_kernel<<<NN * 64 / 256, 256, 0, stream>>>(off, ew, dis, bufA, b1, b2,
                                                      out_mu, out_lv, zhl);

    // Adj = z z^T (XCD-swizzled triangular grid + mirror)
    zz_tri_kernel<<<NTRI, 256, 0, stream>>>(zhl, adj);
}

// Round 10
// 491.510 us; speedup vs baseline: 1.1742x; 1.0006x over previous
//
#include <hip/hip_runtime.h>
#include <hip/hip_bf16.h>

#define NN 16384
#define NE 524288
#define FIN 512
#define HD 256
#define HD2 128
#define NB 128          // NN/128 tile blocks per dim
#define NTRI (NB * (NB + 1) / 2)   // 8256
#define NCHUNK (NTRI / 8)          // 1032 (exact)

typedef __attribute__((ext_vector_type(8))) short bfrag;   // 8 bf16 = 4 VGPRs
typedef __attribute__((ext_vector_type(4))) float ffrag;   // 4 f32 acc

union U8 { ushort u[8]; uint4 v; };

static __device__ __forceinline__ ushort f2bf(float f) {
    uint u = __float_as_uint(f);
    return (ushort)((u + 0x7fff + ((u >> 16) & 1)) >> 16);  // RNE
}
static __device__ __forceinline__ float bf2f(ushort h) {
    return __uint_as_float(((uint)h) << 16);
}

// direct global->LDS 16B copy (linear LDS dest = wave base + lane*16)
static __device__ __forceinline__ void gload16(void* lds, const void* g) {
    __builtin_amdgcn_global_load_lds(
        (const __attribute__((address_space(1))) unsigned int*)g,
        (__attribute__((address_space(3))) unsigned int*)lds, 16, 0, 0);
}

// ---------------- fused: edge-degree count + hi/lo conversions ----------------
__global__ __launch_bounds__(256) void pre_kernel(const int* __restrict__ col,
                                                  int* __restrict__ cnt,
                                                  const float* __restrict__ x,
                                                  const float* __restrict__ W_enc,
                                                  const float* __restrict__ W1,
                                                  const float* __restrict__ W2,
                                                  ushort* __restrict__ xhl,
                                                  ushort* __restrict__ wencT,
                                                  ushort* __restrict__ wcatT) {
    const int b = blockIdx.x, tid = threadIdx.x;
    if (b < 2048) {
        atomicAdd(&cnt[col[b * 256 + tid]], 1);
        return;
    }
    U8 hi, lo;
    if (b < 6144) {  // x path: NN*64 chunk-tasks
        const int t = (b - 2048) * 256 + tid;
        const int r = t >> 6, ci = t & 63;
        const int seg = ci >> 3, c = ci & 7;
        const float* src = x + (size_t)r * FIN + ci * 8;
#pragma unroll
        for (int u = 0; u < 8; ++u) {
            float v = src[u];
            ushort h = f2bf(v);
            hi.u[u] = h;
            lo.u[u] = f2bf(v - bf2f(h));
        }
        ushort* dst = xhl + (size_t)r * (FIN * 2) + seg * 128 + ((c ^ (r & 7)) * 8);
        *(uint4*)dst = hi.v;
        *(uint4*)(dst + 64) = lo.v;
    } else if (b < 6208) {  // Wenc^T: 256 out-rows x 64 chunks
        const int t = (b - 6144) * 256 + tid;
        const int n = t >> 6, ci = t & 63;
        const int seg = ci >> 3, c = ci & 7;
#pragma unroll
        for (int u = 0; u < 8; ++u) {
            float v = W_enc[(size_t)(ci * 8 + u) * HD + n];
            ushort h = f2bf(v);
            hi.u[u] = h;
            lo.u[u] = f2bf(v - bf2f(h));
        }
        ushort* dst = wencT + (size_t)n * (FIN * 2) + seg * 128 + ((c ^ (n & 7)) * 8);
        *(uint4*)dst = hi.v;
        *(uint4*)(dst + 64) = lo.v;
    } else {  // Wcat^T = [W1|W2]^T: 256 out-rows x 32 chunks
        const int t = (b - 6208) * 256 + tid;
        const int n = t >> 5, ci = t & 31;
        const int seg = ci >> 3, c = ci & 7;
#pragma unroll
        for (int u = 0; u < 8; ++u) {
            const int k = ci * 8 + u;
            float v = (n < HD2) ? W1[(size_t)k * HD2 + n] : W2[(size_t)k * HD2 + (n - HD2)];
            ushort h = f2bf(v);
            hi.u[u] = h;
            lo.u[u] = f2bf(v - bf2f(h));
        }
        ushort* dst = wcatT + (size_t)n * (HD * 2) + seg * 128 + ((c ^ (n & 7)) * 8);
        *(uint4*)dst = hi.v;
        *(uint4*)(dst + 64) = lo.v;
    }
}

// exclusive scan of counts + dis = rsqrt(cnt+1) fused
__global__ __launch_bounds__(256) void scan_kernel(const int* __restrict__ cnt,
                                                   int* __restrict__ off,
                                                   float* __restrict__ dis) {
    __shared__ int part[256];
    const int t = threadIdx.x;
    const int base = t * 64;
    int s = 0;
#pragma unroll 4
    for (int j = 0; j < 64; ++j) s += cnt[base + j];
    part[t] = s;
    __syncthreads();
    for (int d = 1; d < 256; d <<= 1) {
        int v = (t >= d) ? part[t - d] : 0;
        __syncthreads();
        part[t] += v;
        __syncthreads();
    }
    int run = (t == 0) ? 0 : part[t - 1];
    for (int j = 0; j < 64; ++j) {
        const int cv = cnt[base + j];
        off[base + j] = run;
        run += cv;
        dis[base + j] = rsqrtf((float)cv + 1.0f);
    }
    if (t == 255) off[NN] = run;
}

// pack (src, weight-bits) per edge
__global__ __launch_bounds__(256) void fill_kernel(const int* __restrict__ ei,
                                                   const int* __restrict__ off,
                                                   int* __restrict__ cur,
                                                   const float* __restrict__ dis,
                                                   int2* __restrict__ ew, int E) {
    int e = blockIdx.x * blockDim.x + threadIdx.x;
    if (e >= E) return;
    int r = ei[e], c = ei[E + e];
    int pos = off[c] + atomicAdd(&cur[c], 1);
    int2 p; p.x = r; p.y = __float_as_int(dis[r]);
    ew[pos] = p;
}

// ---------------- generic hi/lo GEMM (3-product): C[M][256] = Ahl . Bhl^T ----------------
__global__ __launch_bounds__(256, 2) void hl_gemm_kernel(const ushort* __restrict__ A,
                                                         const ushort* __restrict__ B,
                                                         float* __restrict__ C,
                                                         int nseg) {
    __shared__ ushort Ash[128 * 128];
    __shared__ ushort Bsh[128 * 128];
    const int tid = threadIdx.x;
    const int lane = tid & 63, wid = tid >> 6;
    const int rA0 = blockIdx.y * 128, cB0 = blockIdx.x * 128;
    const int rowush = nseg * 128;
    const int wm = (wid >> 1) * 64, wn = (wid & 1) * 64;
    const int fr = lane & 15, g = lane >> 4;

    ffrag acc[4][4];
#pragma unroll
    for (int i = 0; i < 4; ++i)
#pragma unroll
        for (int j = 0; j < 4; ++j) acc[i][j] = (ffrag){0.f, 0.f, 0.f, 0.f};

    for (int s = 0; s < nseg; ++s) {
        if (s) __syncthreads();
#pragma unroll
        for (int it = 0; it < 8; ++it) {
            int idx = it * 256 + tid;
            int row = idx >> 4, c16 = idx & 15;
            gload16(&Ash[idx * 8], &A[(size_t)(rA0 + row) * rowush + s * 128 + c16 * 8]);
            gload16(&Bsh[idx * 8], &B[(size_t)(cB0 + row) * rowush + s * 128 + c16 * 8]);
        }
        __syncthreads();
#pragma unroll
        for (int m = 0; m < 2; ++m) {
            bfrag ah[4], al[4], bh[4], bl[4];
            const int sw = ((m * 4 + g) ^ (fr & 7)) * 8;
#pragma unroll
            for (int mf = 0; mf < 4; ++mf) {
                const int base = (wm + mf * 16 + fr) * 128;
                ah[mf] = *(const bfrag*)&Ash[base + sw];
                al[mf] = *(const bfrag*)&Ash[base + 64 + sw];
            }
#pragma unroll
            for (int nf = 0; nf < 4; ++nf) {
                const int base = (wn + nf * 16 + fr) * 128;
                bh[nf] = *(const bfrag*)&Bsh[base + sw];
                bl[nf] = *(const bfrag*)&Bsh[base + 64 + sw];
            }
#pragma unroll
            for (int mf = 0; mf < 4; ++mf)
#pragma unroll
                for (int nf = 0; nf < 4; ++nf) {
                    acc[mf][nf] = __builtin_amdgcn_mfma_f32_16x16x32_bf16(ah[mf], bh[nf], acc[mf][nf], 0, 0, 0);
                    acc[mf][nf] = __builtin_amdgcn_mfma_f32_16x16x32_bf16(ah[mf], bl[nf], acc[mf][nf], 0, 0, 0);
                    acc[mf][nf] = __builtin_amdgcn_mfma_f32_16x16x32_bf16(al[mf], bh[nf], acc[mf][nf], 0, 0, 0);
                }
        }
    }
    const size_t row0 = (size_t)rA0 + wm;
    const int col0 = cB0 + wn;
#pragma unroll
    for (int mf = 0; mf < 4; ++mf)
#pragma unroll
        for (int reg = 0; reg < 4; ++reg) {
            float* outp = C + (row0 + mf * 16 + g * 4 + reg) * HD + col0 + fr;
#pragma unroll
            for (int nf = 0; nf < 4; ++nf) outp[nf * 16] = acc[mf][nf][reg];
        }
}

// ---------------- gather layer 1: relu(bias + norm-agg) -> h_hl ----------------
__global__ __launch_bounds__(256) void gather0_kernel(const int* __restrict__ off,
                                                      const int2* __restrict__ ew,
                                                      const float* __restrict__ dis,
                                                      const float* __restrict__ A,
                                                      const float* __restrict__ bias,
                                                      ushort* __restrict__ hhl) {
    const int i = __builtin_amdgcn_readfirstlane((blockIdx.x * blockDim.x + threadIdx.x) >> 6);
    const int lane = threadIdx.x & 63;
    const float di = dis[i];
    const int j = lane * 4;
    float4 a0 = *(const float4*)&A[(size_t)i * HD + j];
    a0.x *= di; a0.y *= di; a0.z *= di; a0.w *= di;
    float4 s1 = make_float4(0.f, 0.f, 0.f, 0.f);
    float4 s2 = make_float4(0.f, 0.f, 0.f, 0.f);
    float4 s3 = make_float4(0.f, 0.f, 0.f, 0.f);
    const int k1 = off[i + 1];
    int k = off[i];
    for (; k + 4 <= k1; k += 4) {
        const int2 e0 = ew[k], e1 = ew[k + 1], e2 = ew[k + 2], e3 = ew[k + 3];
        const float w0 = __int_as_float(e0.y), w1 = __int_as_float(e1.y);
        const float w2 = __int_as_float(e2.y), w3 = __int_as_float(e3.y);
        const float4 v0 = *(const float4*)&A[(size_t)e0.x * HD + j];
        const float4 v1 = *(const float4*)&A[(size_t)e1.x * HD + j];
        const float4 v2 = *(const float4*)&A[(size_t)e2.x * HD + j];
        const float4 v3 = *(const float4*)&A[(size_t)e3.x * HD + j];
        a0.x += w0 * v0.x; a0.y += w0 * v0.y; a0.z += w0 * v0.z; a0.w += w0 * v0.w;
        s1.x += w1 * v1.x; s1.y += w1 * v1.y; s1.z += w1 * v1.z; s1.w += w1 * v1.w;
        s2.x += w2 * v2.x; s2.y += w2 * v2.y; s2.z += w2 * v2.z; s2.w += w2 * v2.w;
        s3.x += w3 * v3.x; s3.y += w3 * v3.y; s3.z += w3 * v3.z; s3.w += w3 * v3.w;
    }
    for (; k < k1; ++k) {
        const int2 e0 = ew[k];
        const float w0 = __int_as_float(e0.y);
        const float4 v0 = *(const float4*)&A[(size_t)e0.x * HD + j];
        a0.x += w0 * v0.x; a0.y += w0 * v0.y; a0.z += w0 * v0.z; a0.w += w0 * v0.w;
    }
    a0.x += s1.x + s2.x + s3.x;
    a0.y += s1.y + s2.y + s3.y;
    a0.z += s1.z + s2.z + s3.z;
    a0.w += s1.w + s2.w + s3.w;
    const float4 bb = *(const float4*)&bias[j];
    a0.x = fmaxf(a0.x * di + bb.x, 0.f);
    a0.y = fmaxf(a0.y * di + bb.y, 0.f);
    a0.z = fmaxf(a0.z * di + bb.z, 0.f);
    a0.w = fmaxf(a0.w * di + bb.w, 0.f);
    ushort4 hv, lv;
    hv.x = f2bf(a0.x); lv.x = f2bf(a0.x - bf2f(hv.x));
    hv.y = f2bf(a0.y); lv.y = f2bf(a0.y - bf2f(hv.y));
    hv.z = f2bf(a0.z); lv.z = f2bf(a0.z - bf2f(hv.z));
    hv.w = f2bf(a0.w); lv.w = f2bf(a0.w - bf2f(hv.w));
    const int seg = lane >> 4, c = (lane >> 1) & 7, half = (lane & 1) * 4;
    ushort* dst = hhl + (size_t)i * (HD * 2) + seg * 128 + ((c ^ (i & 7)) * 8) + half;
    *(ushort4*)dst = hv;
    *(ushort4*)(dst + 64) = lv;
}

// ---------------- gather layer 2: mu/logvar f32 out + z_hl ----------------
__global__ __launch_bounds__(256) void gather1_kernel(const int* __restrict__ off,
                                                      const int2* __restrict__ ew,
                                                      const float* __restrict__ dis,
                                                      const float* __restrict__ A,
                                                      const float* __restrict__ b1,
                                                      const float* __restrict__ b2,
                                                      float* __restrict__ out_mu,
                                                      float* __restrict__ out_lv,
                                                      ushort* __restrict__ zhl) {
    const int i = __builtin_amdgcn_readfirstlane((blockIdx.x * blockDim.x + threadIdx.x) >> 6);
    const int lane = threadIdx.x & 63;
    const float di = dis[i];
    const int j = lane * 4;
    float4 a0 = *(const float4*)&A[(size_t)i * HD + j];
    a0.x *= di; a0.y *= di; a0.z *= di; a0.w *= di;
    float4 s1 = make_float4(0.f, 0.f, 0.f, 0.f);
    float4 s2 = make_float4(0.f, 0.f, 0.f, 0.f);
    float4 s3 = make_float4(0.f, 0.f, 0.f, 0.f);
    const int k1 = off[i + 1];
    int k = off[i];
    for (; k + 4 <= k1; k += 4) {
        const int2 e0 = ew[k], e1 = ew[k + 1], e2 = ew[k + 2], e3 = ew[k + 3];
        const float w0 = __int_as_float(e0.y), w1 = __int_as_float(e1.y);
        const float w2 = __int_as_float(e2.y), w3 = __int_as_float(e3.y);
        const float4 v0 = *(const float4*)&A[(size_t)e0.x * HD + j];
        const float4 v1 = *(const float4*)&A[(size_t)e1.x * HD + j];
        const float4 v2 = *(const float4*)&A[(size_t)e2.x * HD + j];
        const float4 v3 = *(const float4*)&A[(size_t)e3.x * HD + j];
        a0.x += w0 * v0.x; a0.y += w0 * v0.y; a0.z += w0 * v0.z; a0.w += w0 * v0.w;
        s1.x += w1 * v1.x; s1.y += w1 * v1.y; s1.z += w1 * v1.z; s1.w += w1 * v1.w;
        s2.x += w2 * v2.x; s2.y += w2 * v2.y; s2.z += w2 * v2.z; s2.w += w2 * v2.w;
        s3.x += w3 * v3.x; s3.y += w3 * v3.y; s3.z += w3 * v3.z; s3.w += w3 * v3.w;
    }
    for (; k < k1; ++k) {
        const int2 e0 = ew[k];
        const float w0 = __int_as_float(e0.y);
        const float4 v0 = *(const float4*)&A[(size_t)e0.x * HD + j];
        a0.x += w0 * v0.x; a0.y += w0 * v0.y; a0.z += w0 * v0.z; a0.w += w0 * v0.w;
    }
    float4 r;
    r.x = (a0.x + s1.x + s2.x + s3.x) * di;
    r.y = (a0.y + s1.y + s2.y + s3.y) * di;
    r.z = (a0.z + s1.z + s2.z + s3.z) * di;
    r.w = (a0.w + s1.w + s2.w + s3.w) * di;
    if (lane < 32) {
        const float4 bb = *(const float4*)&b1[j];
        r.x += bb.x; r.y += bb.y; r.z += bb.z; r.w += bb.w;
        *(float4*)&out_mu[(size_t)i * HD2 + j] = r;
        ushort4 hv, lv;
        hv.x = f2bf(r.x); lv.x = f2bf(r.x - bf2f(hv.x));
        hv.y = f2bf(r.y); lv.y = f2bf(r.y - bf2f(hv.y));
        hv.z = f2bf(r.z); lv.z = f2bf(r.z - bf2f(hv.z));
        hv.w = f2bf(r.w); lv.w = f2bf(r.w - bf2f(hv.w));
        const int seg = lane >> 4, c = (lane >> 1) & 7, half = (lane & 1) * 4;
        ushort* dst = zhl + (size_t)i * (HD2 * 2) + seg * 128 + ((c ^ (i & 7)) * 8) + half;
        *(ushort4*)dst = hv;
        *(ushort4*)(dst + 64) = lv;
    } else {
        const int jj = j - HD2;
        const float4 bb = *(const float4*)&b2[jj];
        r.x += bb.x; r.y += bb.y; r.z += bb.z; r.w += bb.w;
        *(float4*)&out_lv[(size_t)i * HD2 + jj] = r;
    }
}

// ---------------- Adj = z z^T, XCD-swizzled 1D triangular grid + mirror ----------------
__global__ __launch_bounds__(256, 2) void zz_tri_kernel(const ushort* __restrict__ Z,
                                                        float* __restrict__ adj) {
    const int orig = blockIdx.x;
    const int t = (orig & 7) * NCHUNK + (orig >> 3);
    int bm = (int)((257.0f - sqrtf(66049.0f - 8.0f * (float)t)) * 0.5f);
    while (bm * NB - bm * (bm - 1) / 2 > t) --bm;
    while ((bm + 1) * NB - (bm + 1) * bm / 2 <= t) ++bm;
    const int bn = bm + (t - (bm * NB - bm * (bm - 1) / 2));

    __shared__ ushort Ash[128 * 128];
    __shared__ ushort Bsh[128 * 128];
    const int tid = threadIdx.x;
    const int lane = tid & 63, wid = tid >> 6;
    const int wm = (wid >> 1) * 64, wn = (wid & 1) * 64;
    const int fr = lane & 15, g = lane >> 4;

    ffrag acc[4][4];
#pragma unroll
    for (int i = 0; i < 4; ++i)
#pragma unroll
        for (int j = 0; j < 4; ++j) acc[i][j] = (ffrag){0.f, 0.f, 0.f, 0.f};

#pragma unroll
    for (int s = 0; s < 2; ++s) {
        if (s) __syncthreads();
#pragma unroll
        for (int it = 0; it < 8; ++it) {
            int idx = it * 256 + tid;
            int row = idx >> 4, c16 = idx & 15;
            gload16(&Ash[idx * 8], &Z[(size_t)(bm * 128 + row) * 256 + s * 128 + c16 * 8]);
            gload16(&Bsh[idx * 8], &Z[(size_t)(bn * 128 + row) * 256 + s * 128 + c16 * 8]);
        }
        __syncthreads();
#pragma unroll
        for (int m = 0; m < 2; ++m) {
            bfrag ah[4], al[4], bh[4], bl[4];
            const int sw = ((m * 4 + g) ^ (fr & 7)) * 8;
#pragma unroll
            for (int mf = 0; mf < 4; ++mf) {
                const int base = (wm + mf * 16 + fr) * 128;
                ah[mf] = *(const bfrag*)&Ash[base + sw];
                al[mf] = *(const bfrag*)&Ash[base + 64 + sw];
            }
#pragma unroll
            for (int nf = 0; nf < 4; ++nf) {
                const int base = (wn + nf * 16 + fr) * 128;
                bh[nf] = *(const bfrag*)&Bsh[base + sw];
                bl[nf] = *(const bfrag*)&Bsh[base + 64 + sw];
            }
#pragma unroll
            for (int mf = 0; mf < 4; ++mf)
#pragma unroll
                for (int nf = 0; nf < 4; ++nf) {
                    acc[mf][nf] = __builtin_amdgcn_mfma_f32_16x16x32_bf16(ah[mf], bh[nf], acc[mf][nf], 0, 0, 0);
                    acc[mf][nf] = __builtin_amdgcn_mfma_f32_16x16x32_bf16(ah[mf], bl[nf], acc[mf][nf], 0, 0, 0);
                    acc[mf][nf] = __builtin_amdgcn_mfma_f32_16x16x32_bf16(al[mf], bh[nf], acc[mf][nf], 0, 0, 0);
                }
        }
    }

    // normal store (upper tile), cached
    const size_t row0 = (size_t)bm * 128 + wm;
    const int col0 = bn * 128 + wn;
#pragma unroll
    for (int mf = 0; mf < 4; ++mf)
#pragma unroll
        for (int reg = 0; reg < 4; ++reg) {
            float* outp = adj + (row0 + mf * 16 + g * 4 + reg) * NN + col0 + fr;
#pragma unroll
            for (int nf = 0; nf < 4; ++nf) outp[nf * 16] = acc[mf][nf][reg];
        }
    // mirror store (lower tile)
    if (bm != bn) {
#pragma unroll
        for (int nf = 0; nf < 4; ++nf)
#pragma unroll
            for (int mf = 0; mf < 4; ++mf) {
                const size_t addr = ((size_t)bn * 128 + wn + nf * 16 + fr) * NN
                                  + (size_t)bm * 128 + wm + mf * 16 + g * 4;
                *(float4*)&adj[addr] = *(float4*)&acc[mf][nf];
            }
    }
}

extern "C" void kernel_launch(void* const* d_in, const int* in_sizes, int n_in,
                              void* d_out, int out_size, void* d_ws, size_t ws_size,
                              hipStream_t stream) {
    const float* x     = (const float*)d_in[0];
    const int*   ei    = (const int*)d_in[1];
    const float* W_enc = (const float*)d_in[2];
    const float* b_enc = (const float*)d_in[3];
    const float* W1    = (const float*)d_in[4];
    const float* b1    = (const float*)d_in[5];
    const float* W2    = (const float*)d_in[6];
    const float* b2    = (const float*)d_in[7];

    float* out    = (float*)d_out;
    float* adj    = out;
    float* out_mu = out + (size_t)NN * NN;
    float* out_lv = out_mu + (size_t)NN * HD2;

    float*  ws    = (float*)d_ws;
    float*  dis   = ws;                                  // NN f32
    float*  bufA  = ws + NN;                             // NN*HD f32
    ushort* xhl   = (ushort*)(bufA + (size_t)NN * HD);   // NN*1024 ush
    ushort* hhl   = xhl;                                 // reuse after gemm1 (NN*512 ush)
    ushort* zhl   = xhl + (size_t)NN * 512;              // reuse tail (NN*256 ush)
    ushort* wencT = xhl + (size_t)NN * 1024;             // 256*1024 ush
    ushort* wcatT = wencT + 256 * 1024;                  // 256*512 ush
    int2*   ew    = (int2*)(wcatT + 256 * 512);          // NE int2
    int*    icnt  = (int*)(ew + NE);                     // NN
    int*    off   = icnt + NN;                           // NN+1
    int*    cur   = off + NN + 1;                        // NN

    hipMemsetAsync(icnt, 0, NN * sizeof(int), stream);
    hipMemsetAsync(cur, 0, NN * sizeof(int), stream);

    pre_kernel<<<6240, 256, 0, stream>>>(ei + NE, icnt, x, W_enc, W1, W2,
                                         xhl, wencT, wcatT);
    scan_kernel<<<1, 256, 0, stream>>>(icnt, off, dis);
    fill_kernel<<<NE / 256, 256, 0, stream>>>(ei, off, cur, dis, ew, NE);

    hl_gemm_kernel<<<dim3(2, NN / 128), 256, 0, stream>>>(xhl, wencT, bufA, FIN / 64);
    gather0_kernel<<<NN * 64 / 256, 256, 0, stream>>>(off, ew, dis, bufA, b_enc, hhl);

    hl_gemm_kernel<<<dim3(2, NN / 128), 256, 0, stream>>>(hhl, wcatT, bufA, HD / 64);
    gather1_kernel<<<NN * 64 / 256, 256, 0, stream>>>(off, ew, dis, bufA, b1, b2,
                                                      out_mu, out_lv, zhl);

    zz_tri_kernel<<<NTRI, 256, 0, stream>>>(zhl, adj);
}